// Round 2
// baseline (1177.431 us; speedup 1.0000x reference)
//
#include <hip/hip_runtime.h>
#include <hip/hip_bf16.h>
#include <math.h>

#define NN 16384      // H*W per image
#define WW 128
#define CDIM 192
#define NHEADS 4
#define DHh 48
#define HIDD 510
#define BB 2

typedef __hip_bfloat16 bf16;

__device__ __forceinline__ float bf2f(unsigned short u) {
    union { unsigned int i; float f; } v; v.i = ((unsigned int)u) << 16; return v.f;
}
__device__ __forceinline__ unsigned short f2bf(float f) {
    union { unsigned int i; float f; } v; v.f = f;
    unsigned int i = v.i;
    return (unsigned short)((i + 0x7fffu + ((i >> 16) & 1u)) >> 16);  // RNE
}

// ---------------- BiasFree LayerNorm over channel dim (one image) ----------
// y[c,n] = x[c,n] * rsqrt(var_n + 1e-5) * w[c]
__global__ __launch_bounds__(256) void ln_kernel(const float* __restrict__ x,
                                                 const float* __restrict__ w,
                                                 bf16* __restrict__ y) {
    int n = blockIdx.x * 256 + threadIdx.x;   // over N
    const float* xp = x + n;
    float s = 0.f, s2 = 0.f;
    for (int c = 0; c < CDIM; ++c) {
        float v = xp[(size_t)c * NN];
        s += v; s2 += v * v;
    }
    const float inv = 1.f / (float)CDIM;
    float mu  = s * inv;
    float var = s2 * inv - mu * mu;
    float rs  = rsqrtf(var + 1e-5f);
    unsigned short* yp = (unsigned short*)y + n;
    for (int c = 0; c < CDIM; ++c)
        yp[(size_t)c * NN] = f2bf(xp[(size_t)c * NN] * rs * w[c]);
}

// ---------------- tiled GEMM (one image): Y[o,n] = sum_c W[o,c]*X[c,n] (+R) --
// MODE 0: Y bf16           MODE 1: Y f32           MODE 2: Y f32, += R (f32)
#define TO 64
#define TNt 128
#define TK 16

template<int MODE>
__global__ __launch_bounds__(256) void gemm_k(
    const float* __restrict__ Wm,   // [O, K] row-major f32
    const bf16*  __restrict__ X,    // [K, N] bf16
    const float* __restrict__ R,    // [O, N] f32 or nullptr (may alias Y)
    void* __restrict__ Yv,          // [O, N]
    int O, int K)
{
    __shared__ float Wt[TK][TO];
    __shared__ float Xt[TK][TNt];
    int n0 = blockIdx.x * TNt;
    int o0 = blockIdx.y * TO;

    int tid = threadIdx.x;
    int tn = (tid & 15) * 8;    // 0..120
    int to = (tid >> 4) * 4;    // 0..60
    float acc[4][8] = {};

    for (int k0 = 0; k0 < K; k0 += TK) {
        {   // W tile: 16x64 = 1024 f32, 4 per thread
            int e = tid;
            #pragma unroll
            for (int r = 0; r < 4; ++r, e += 256) {
                int i = e >> 4, j = e & 15;       // i=o, j=k
                int oo = o0 + i, kk = k0 + j;
                Wt[j][i] = (oo < O && kk < K) ? Wm[(size_t)oo * K + kk] : 0.f;
            }
        }
        {   // X tile: 16x128 bf16, each thread loads 8 contiguous bf16 (16B)
            int j  = tid >> 4;          // k row 0..15
            int i0 = (tid & 15) * 8;    // n col
            int kk = k0 + j;
            if (kk < K) {
                uint4 u = *(const uint4*)((const unsigned short*)X + (size_t)kk * NN + n0 + i0);
                unsigned int uw[4] = {u.x, u.y, u.z, u.w};
                #pragma unroll
                for (int q = 0; q < 4; ++q) {
                    Xt[j][i0 + 2 * q]     = bf2f((unsigned short)(uw[q] & 0xffff));
                    Xt[j][i0 + 2 * q + 1] = bf2f((unsigned short)(uw[q] >> 16));
                }
            } else {
                #pragma unroll
                for (int q = 0; q < 8; ++q) Xt[j][i0 + q] = 0.f;
            }
        }
        __syncthreads();
        #pragma unroll
        for (int j = 0; j < TK; ++j) {
            float4 a  = *(const float4*)&Wt[j][to];
            float4 x0 = *(const float4*)&Xt[j][tn];
            float4 x1 = *(const float4*)&Xt[j][tn + 4];
            float av[4] = {a.x, a.y, a.z, a.w};
            float xv[8] = {x0.x, x0.y, x0.z, x0.w, x1.x, x1.y, x1.z, x1.w};
            #pragma unroll
            for (int p = 0; p < 4; ++p)
                #pragma unroll
                for (int q = 0; q < 8; ++q)
                    acc[p][q] = fmaf(av[p], xv[q], acc[p][q]);
        }
        __syncthreads();
    }
    #pragma unroll
    for (int p = 0; p < 4; ++p) {
        int oo = o0 + to + p;
        if (oo >= O) continue;
        size_t base = (size_t)oo * NN + n0 + tn;
        if (MODE == 0) {
            unsigned int w[4];
            #pragma unroll
            for (int q = 0; q < 4; ++q)
                w[q] = (unsigned int)f2bf(acc[p][2 * q]) |
                       ((unsigned int)f2bf(acc[p][2 * q + 1]) << 16);
            *(uint4*)((unsigned short*)Yv + base) = make_uint4(w[0], w[1], w[2], w[3]);
        } else {
            float v[8];
            #pragma unroll
            for (int q = 0; q < 8; ++q) v[q] = acc[p][q];
            if (MODE == 2) {
                float4 r0 = *(const float4*)&R[base];
                float4 r1 = *(const float4*)&R[base + 4];
                v[0] += r0.x; v[1] += r0.y; v[2] += r0.z; v[3] += r0.w;
                v[4] += r1.x; v[5] += r1.y; v[6] += r1.z; v[7] += r1.w;
            }
            float* Y = (float*)Yv;
            *(float4*)&Y[base]     = make_float4(v[0], v[1], v[2], v[3]);
            *(float4*)&Y[base + 4] = make_float4(v[4], v[5], v[6], v[7]);
        }
    }
}

// ---------------- deformable attention core (one image) ----------------
// one thread per (head, pixel)
__global__ __launch_bounds__(256) void attn_kernel(
    const bf16*  __restrict__ qkv,  // [576, N]  (q:0..191, k:192..383, v:384..575)
    const float* __restrict__ off,  // [72, N]   channel = h*18 + kpt*2 + {0:y,1:x}
    const float* __restrict__ rpb,  // [4, 9]
    bf16* __restrict__ out)         // [192, N]
{
    int idx = blockIdx.x * 256 + threadIdx.x;  // over HEADS*N = 65536
    int n = idx & (NN - 1);
    int h = idx >> 14;
    int py = n >> 7, px = n & 127;

    const unsigned short* base = (const unsigned short*)qkv;
    const unsigned short* qp = base + (size_t)(h * DHh) * NN + n;
    const unsigned short* kp = base + (size_t)(CDIM + h * DHh) * NN;
    const unsigned short* vp = base + (size_t)(2 * CDIM + h * DHh) * NN;
    const float* op = off + (size_t)(h * 18) * NN + n;

    float wgt[9][4];
    int   ofs[9][4];
    float logits[9];
    #pragma unroll
    for (int kpt = 0; kpt < 9; ++kpt) {
        float oy = op[(size_t)(kpt * 2 + 0) * NN];
        float ox = op[(size_t)(kpt * 2 + 1) * NN];
        float cy = fminf(fmaxf((float)(py + (kpt / 3) - 1) + oy, 0.f), 127.f);
        float cx = fminf(fmaxf((float)(px + (kpt % 3) - 1) + ox, 0.f), 127.f);
        float y0f = floorf(cy), x0f = floorf(cx);
        float wy = cy - y0f, wx = cx - x0f;
        int y0 = (int)y0f, x0 = (int)x0f;
        int y1 = min(y0 + 1, 127), x1 = min(x0 + 1, 127);
        ofs[kpt][0] = y0 * WW + x0;  wgt[kpt][0] = (1.f - wy) * (1.f - wx);
        ofs[kpt][1] = y0 * WW + x1;  wgt[kpt][1] = (1.f - wy) * wx;
        ofs[kpt][2] = y1 * WW + x0;  wgt[kpt][2] = wy * (1.f - wx);
        ofs[kpt][3] = y1 * WW + x1;  wgt[kpt][3] = wy * wx;
        logits[kpt] = 0.f;
    }
    for (int c = 0; c < DHh; ++c) {
        const unsigned short* kc = kp + (size_t)c * NN;
        float qv = bf2f(qp[(size_t)c * NN]);
        #pragma unroll
        for (int kpt = 0; kpt < 9; ++kpt) {
            float ks = wgt[kpt][0] * bf2f(kc[ofs[kpt][0]])
                     + wgt[kpt][1] * bf2f(kc[ofs[kpt][1]])
                     + wgt[kpt][2] * bf2f(kc[ofs[kpt][2]])
                     + wgt[kpt][3] * bf2f(kc[ofs[kpt][3]]);
            logits[kpt] = fmaf(qv, ks, logits[kpt]);
        }
    }
    #pragma unroll
    for (int kpt = 0; kpt < 9; ++kpt)
        logits[kpt] = logits[kpt] * 0.14433756729740643f + rpb[h * 9 + kpt];

    float m = logits[0];
    #pragma unroll
    for (int i = 1; i < 9; ++i) m = fmaxf(m, logits[i]);
    float aw[9]; float ssum = 0.f;
    #pragma unroll
    for (int i = 0; i < 9; ++i) { aw[i] = __expf(logits[i] - m); ssum += aw[i]; }
    float inv = 1.f / ssum;
    #pragma unroll
    for (int i = 0; i < 9; ++i) aw[i] *= inv;

    unsigned short* o = (unsigned short*)out + (size_t)(h * DHh) * NN + n;
    for (int c = 0; c < DHh; ++c) {
        const unsigned short* vc = vp + (size_t)c * NN;
        float acc = 0.f;
        #pragma unroll
        for (int kpt = 0; kpt < 9; ++kpt) {
            float vs = wgt[kpt][0] * bf2f(vc[ofs[kpt][0]])
                     + wgt[kpt][1] * bf2f(vc[ofs[kpt][1]])
                     + wgt[kpt][2] * bf2f(vc[ofs[kpt][2]])
                     + wgt[kpt][3] * bf2f(vc[ofs[kpt][3]]);
            acc = fmaf(aw[kpt], vs, acc);
        }
        o[(size_t)c * NN] = f2bf(acc);
    }
}

// ------- depthwise 3x3 conv (both halves) + exact-GELU gate (one image) -----
__global__ __launch_bounds__(256) void dwgate_kernel(
    const bf16* __restrict__ t,     // [1020, N]
    const float* __restrict__ dww,  // [1020, 9]
    bf16* __restrict__ g)           // [510, N]
{
    int idx = blockIdx.x * 256 + threadIdx.x;  // over 510*N
    int n = idx & (NN - 1);
    int c = idx >> 14;
    int y = n >> 7, x = n & 127;
    const unsigned short* t1 = (const unsigned short*)t + (size_t)c * NN;
    const unsigned short* t2 = t1 + (size_t)HIDD * NN;
    const float* w1 = dww + c * 9;
    const float* w2 = dww + (c + HIDD) * 9;
    float a1 = 0.f, a2 = 0.f;
    #pragma unroll
    for (int dy = 0; dy < 3; ++dy) {
        int yy = y + dy - 1;
        if (yy < 0 || yy > 127) continue;
        #pragma unroll
        for (int dx = 0; dx < 3; ++dx) {
            int xx = x + dx - 1;
            if (xx < 0 || xx > 127) continue;
            int nn = yy * WW + xx;
            a1 = fmaf(bf2f(t1[nn]), w1[dy * 3 + dx], a1);
            a2 = fmaf(bf2f(t2[nn]), w2[dy * 3 + dx], a2);
        }
    }
    float ge = 0.5f * a1 * (1.f + erff(a1 * 0.70710678118654752f));
    ((unsigned short*)g)[(size_t)c * NN + n] = f2bf(ge * a2);
}

extern "C" void kernel_launch(void* const* d_in, const int* in_sizes, int n_in,
                              void* d_out, int out_size, void* d_ws, size_t ws_size,
                              hipStream_t stream)
{
    const float* x      = (const float*)d_in[0];
    const float* ln1_w  = (const float*)d_in[1];
    const float* ln2_w  = (const float*)d_in[2];
    const float* qkv_w  = (const float*)d_in[3];
    const float* off_w  = (const float*)d_in[4];
    const float* rpb    = (const float*)d_in[5];
    const float* proj_w = (const float*)d_in[6];
    const float* pi_w   = (const float*)d_in[7];
    const float* dw_w   = (const float*)d_in[8];
    const float* po_w   = (const float*)d_in[9];
    float* out = (float*)d_out;

    // per-image workspace layout (bytes), total 63.3 MB; both batches reuse it
    char* ws = (char*)d_ws;
    bf16*  xn   = (bf16*)ws;                                  // 192*N bf16  = 6.29 MB (also attn, xn2)
    bf16*  qkv  = (bf16*)(ws + (size_t)CDIM * NN * 2);        // 576*N bf16  = 18.9 MB (also g)
    float* offb = (float*)(ws + (size_t)(CDIM + 3 * CDIM) * NN * 2);       // 72*N f32 = 4.7 MB
    bf16*  t    = (bf16*)(ws + (size_t)(4 * CDIM) * NN * 2 + (size_t)72 * NN * 4); // 1020*N bf16 = 33.4 MB
    bf16*  attn = xn;
    bf16*  g    = qkv;

    dim3 blk(256);

    for (int b = 0; b < BB; ++b) {
        const float* xb   = x   + (size_t)b * CDIM * NN;
        float*       outb = out + (size_t)b * CDIM * NN;

        // 1. xn1 = LN1(x)
        ln_kernel<<<dim3(NN / 256), blk, 0, stream>>>(xb, ln1_w, xn);
        // 2. qkv = qkv_w @ xn1   (bf16 out)
        gemm_k<0><<<dim3(NN / TNt, (3 * CDIM) / TO), blk, 0, stream>>>(
            qkv_w, xn, nullptr, qkv, 3 * CDIM, CDIM);
        // 3. off = off_w @ xn1   (f32 out)
        gemm_k<1><<<dim3(NN / TNt, (72 + TO - 1) / TO), blk, 0, stream>>>(
            off_w, xn, nullptr, offb, 72, CDIM);
        // 4. deformable attention (attn aliases xn; xn dead after steps 2-3)
        attn_kernel<<<dim3(NHEADS * NN / 256), blk, 0, stream>>>(qkv, offb, rpb, attn);
        // 5. x1 = x + proj_w @ attn   -> d_out (f32)
        gemm_k<2><<<dim3(NN / TNt, CDIM / TO), blk, 0, stream>>>(
            proj_w, attn, xb, outb, CDIM, CDIM);
        // 6. xn2 = LN2(x1)  (xn region; attn dead)
        ln_kernel<<<dim3(NN / 256), blk, 0, stream>>>(outb, ln2_w, xn);
        // 7. t = pi_w @ xn2  (bf16 out)
        gemm_k<0><<<dim3(NN / TNt, (2 * HIDD + TO - 1) / TO), blk, 0, stream>>>(
            pi_w, xn, nullptr, t, 2 * HIDD, CDIM);
        // 8. g = gelu(dw(t1)) * dw(t2)   (g aliases qkv; qkv dead)
        dwgate_kernel<<<dim3(HIDD * NN / 256), blk, 0, stream>>>(t, dw_w, g);
        // 9. out = x1 + po_w @ g   (in-place residual on d_out)
        gemm_k<2><<<dim3(NN / TNt, CDIM / TO), blk, 0, stream>>>(
            po_w, g, outb, outb, CDIM, HIDD);
    }
}

// Round 3
// 911.408 us; speedup vs baseline: 1.2919x; 1.2919x over previous
//
#include <hip/hip_runtime.h>
#include <hip/hip_bf16.h>
#include <math.h>

#define NN 16384      // H*W per image
#define WW 128
#define CDIM 192
#define NHEADS 4
#define DHh 48
#define HIDD 510
#define BB 2

typedef __hip_bfloat16 bf16;
typedef unsigned short ushort_t;
using short8 = __attribute__((ext_vector_type(8))) short;
using f32x4  = __attribute__((ext_vector_type(4))) float;

__device__ __forceinline__ float bf2f(unsigned short u) {
    union { unsigned int i; float f; } v; v.i = ((unsigned int)u) << 16; return v.f;
}
__device__ __forceinline__ unsigned short f2bf(float f) {
    union { unsigned int i; float f; } v; v.f = f;
    unsigned int i = v.i;
    return (unsigned short)((i + 0x7fffu + ((i >> 16) & 1u)) >> 16);  // RNE
}

// ---------------- weight f32 -> bf16 (with K padding) ----------------
__global__ __launch_bounds__(256) void convw_kernel(const float* __restrict__ src,
                                                    ushort_t* __restrict__ dst,
                                                    int O, int Kin, int Kout) {
    int idx = blockIdx.x * 256 + threadIdx.x;
    if (idx >= O * Kout) return;
    int o = idx / Kout, k = idx - o * Kout;
    dst[idx] = (k < Kin) ? f2bf(src[(size_t)o * Kin + k]) : (ushort_t)0;
}

// ---------------- BiasFree LayerNorm over channel dim (one image) ----------
__global__ __launch_bounds__(256) void ln_kernel(const float* __restrict__ x,
                                                 const float* __restrict__ w,
                                                 ushort_t* __restrict__ y) {
    int n = blockIdx.x * 256 + threadIdx.x;   // over N
    const float* xp = x + n;
    float s = 0.f, s2 = 0.f;
    for (int c = 0; c < CDIM; ++c) {
        float v = xp[(size_t)c * NN];
        s += v; s2 += v * v;
    }
    const float inv = 1.f / (float)CDIM;
    float mu  = s * inv;
    float var = s2 * inv - mu * mu;
    float rs  = rsqrtf(var + 1e-5f);
    ushort_t* yp = y + n;
    for (int c = 0; c < CDIM; ++c)
        yp[(size_t)c * NN] = f2bf(xp[(size_t)c * NN] * rs * w[c]);
}

// ---------------- MFMA GEMM: Y[o,n] = sum_k Wb[o,k]*X[k,n] (+R) ------------
// Wb bf16 [O,K] row-major (K mult of 64). X bf16 [K,N]. Block: 64 n-cols,
// 256 o-rows (4 waves x 64o). LDS: X-tile transposed [64n][K+8].
// MODE 0: Y bf16.  MODE 2: Y f32 = acc + R (f32).
template<int MODE>
__global__ __launch_bounds__(256) void gemm_mfma(
    const ushort_t* __restrict__ Wb,
    const ushort_t* __restrict__ X,
    const float* __restrict__ R,
    void* __restrict__ Yv,
    int O, int K, int KP)
{
    extern __shared__ ushort_t Xt[];   // [64][KP]
    int tid = threadIdx.x;
    int n0 = blockIdx.x * 64;

    // ---- stage X tile transposed: thread owns k = tid&63 (+64 steps), 16 n ----
    {
        int kbase = tid & 63;
        int nb = (tid >> 6) * 16;
        for (int kk = kbase; kk < K; kk += 64) {
            const ushort_t* src = X + (size_t)kk * NN + n0 + nb;
            uint4 u0 = *(const uint4*)src;
            uint4 u1 = *(const uint4*)(src + 8);
            union { uint4 u[2]; ushort_t v[16]; } tb;
            tb.u[0] = u0; tb.u[1] = u1;
            #pragma unroll
            for (int j = 0; j < 16; ++j)
                Xt[(size_t)(nb + j) * KP + kk] = tb.v[j];
        }
    }
    __syncthreads();

    int w = tid >> 6, l = tid & 63;
    int o0w = blockIdx.y * 256 + w * 64;
    if (o0w >= O) return;

    int lrow = l & 15;
    int lk   = (l >> 4) * 8;

    f32x4 acc[4][4] = {};

    for (int kk0 = 0; kk0 < K; kk0 += 32) {
        short8 bfr[4];
        #pragma unroll
        for (int ni = 0; ni < 4; ++ni)
            bfr[ni] = *(const short8*)&Xt[(size_t)(ni * 16 + lrow) * KP + kk0 + lk];
        short8 afr[4];
        #pragma unroll
        for (int mi = 0; mi < 4; ++mi) {
            int orow = o0w + mi * 16 + lrow;
            if (orow < O)
                afr[mi] = *(const short8*)(Wb + (size_t)orow * K + kk0 + lk);
            else
                afr[mi] = short8{0,0,0,0,0,0,0,0};
        }
        #pragma unroll
        for (int mi = 0; mi < 4; ++mi)
            #pragma unroll
            for (int ni = 0; ni < 4; ++ni)
                acc[mi][ni] = __builtin_amdgcn_mfma_f32_16x16x32_bf16(
                    afr[mi], bfr[ni], acc[mi][ni], 0, 0, 0);
    }

    // ---- epilogue: D col=lane&15, row=(lane>>4)*4+r ----
    int orow0 = (l >> 4) * 4;
    #pragma unroll
    for (int mi = 0; mi < 4; ++mi) {
        #pragma unroll
        for (int ni = 0; ni < 4; ++ni) {
            int n = n0 + ni * 16 + lrow;
            #pragma unroll
            for (int r = 0; r < 4; ++r) {
                int orow = o0w + mi * 16 + orow0 + r;
                if (orow >= O) continue;
                size_t idx = (size_t)orow * NN + n;
                float v = acc[mi][ni][r];
                if (MODE == 0) {
                    ((ushort_t*)Yv)[idx] = f2bf(v);
                } else {
                    ((float*)Yv)[idx] = v + (R ? R[idx] : 0.f);
                }
            }
        }
    }
}

// ---------------- deformable attention: 4 lanes per (head, pixel) ----------
__global__ __launch_bounds__(256) void attn_kernel(
    const ushort_t* __restrict__ qkv,  // [576, N]
    const ushort_t* __restrict__ off,  // [72, N] bf16
    const float* __restrict__ rpb,     // [4, 9]
    ushort_t* __restrict__ out)        // [192, N]
{
    int idx = blockIdx.x * 256 + threadIdx.x;  // over HEADS*N*4
    int split = idx & 3;
    int ph = idx >> 2;                 // head*N + n
    int n = ph & (NN - 1);
    int h = ph >> 14;
    int py = n >> 7, px = n & 127;
    int c0 = split * 12;

    const ushort_t* qp = qkv + (size_t)(h * DHh + c0) * NN + n;
    const ushort_t* kp = qkv + (size_t)(CDIM + h * DHh + c0) * NN;
    const ushort_t* vp = qkv + (size_t)(2 * CDIM + h * DHh + c0) * NN;
    const ushort_t* op = off + (size_t)(h * 18) * NN + n;

    float wgt[9][4];
    int   ofs[9][4];
    float logits[9];
    #pragma unroll
    for (int kpt = 0; kpt < 9; ++kpt) {
        float oy = bf2f(op[(size_t)(kpt * 2 + 0) * NN]);
        float ox = bf2f(op[(size_t)(kpt * 2 + 1) * NN]);
        float cy = fminf(fmaxf((float)(py + (kpt / 3) - 1) + oy, 0.f), 127.f);
        float cx = fminf(fmaxf((float)(px + (kpt % 3) - 1) + ox, 0.f), 127.f);
        float y0f = floorf(cy), x0f = floorf(cx);
        float wy = cy - y0f, wx = cx - x0f;
        int y0 = (int)y0f, x0 = (int)x0f;
        int y1 = min(y0 + 1, 127), x1 = min(x0 + 1, 127);
        ofs[kpt][0] = y0 * WW + x0;  wgt[kpt][0] = (1.f - wy) * (1.f - wx);
        ofs[kpt][1] = y0 * WW + x1;  wgt[kpt][1] = (1.f - wy) * wx;
        ofs[kpt][2] = y1 * WW + x0;  wgt[kpt][2] = wy * (1.f - wx);
        ofs[kpt][3] = y1 * WW + x1;  wgt[kpt][3] = wy * wx;
        logits[kpt] = 0.f;
    }
    // partial dot over this lane's 12 channels
    for (int c = 0; c < 12; ++c) {
        const ushort_t* kc = kp + (size_t)c * NN;
        float qv = bf2f(qp[(size_t)c * NN]);
        #pragma unroll
        for (int kpt = 0; kpt < 9; ++kpt) {
            float ks = wgt[kpt][0] * bf2f(kc[ofs[kpt][0]])
                     + wgt[kpt][1] * bf2f(kc[ofs[kpt][1]])
                     + wgt[kpt][2] * bf2f(kc[ofs[kpt][2]])
                     + wgt[kpt][3] * bf2f(kc[ofs[kpt][3]]);
            logits[kpt] = fmaf(qv, ks, logits[kpt]);
        }
    }
    // reduce across the 4 lanes of the group
    #pragma unroll
    for (int kpt = 0; kpt < 9; ++kpt) {
        float v = logits[kpt];
        v += __shfl_xor(v, 1);
        v += __shfl_xor(v, 2);
        logits[kpt] = v * 0.14433756729740643f + rpb[h * 9 + kpt];
    }
    float m = logits[0];
    #pragma unroll
    for (int i = 1; i < 9; ++i) m = fmaxf(m, logits[i]);
    float aw[9]; float ssum = 0.f;
    #pragma unroll
    for (int i = 0; i < 9; ++i) { aw[i] = __expf(logits[i] - m); ssum += aw[i]; }
    float inv = 1.f / ssum;
    #pragma unroll
    for (int i = 0; i < 9; ++i) aw[i] *= inv;

    ushort_t* o = out + (size_t)(h * DHh + c0) * NN + n;
    for (int c = 0; c < 12; ++c) {
        const ushort_t* vc = vp + (size_t)c * NN;
        float acc = 0.f;
        #pragma unroll
        for (int kpt = 0; kpt < 9; ++kpt) {
            float vs = wgt[kpt][0] * bf2f(vc[ofs[kpt][0]])
                     + wgt[kpt][1] * bf2f(vc[ofs[kpt][1]])
                     + wgt[kpt][2] * bf2f(vc[ofs[kpt][2]])
                     + wgt[kpt][3] * bf2f(vc[ofs[kpt][3]]);
            acc = fmaf(aw[kpt], vs, acc);
        }
        o[(size_t)c * NN] = f2bf(acc);
    }
}

// ------- depthwise 3x3 conv (both halves) + exact-GELU gate; 512-ch padded --
__global__ __launch_bounds__(256) void dwgate_kernel(
    const ushort_t* __restrict__ t,   // [1020, N]
    const float* __restrict__ dww,    // [1020, 9]
    ushort_t* __restrict__ g)         // [512, N] (c>=510 zero)
{
    int idx = blockIdx.x * 256 + threadIdx.x;  // over 512*N
    int n = idx & (NN - 1);
    int c = idx >> 14;
    if (c >= HIDD) { g[(size_t)c * NN + n] = 0; return; }
    int y = n >> 7, x = n & 127;
    const ushort_t* t1 = t + (size_t)c * NN;
    const ushort_t* t2 = t1 + (size_t)HIDD * NN;
    const float* w1 = dww + c * 9;
    const float* w2 = dww + (c + HIDD) * 9;
    float a1 = 0.f, a2 = 0.f;
    #pragma unroll
    for (int dy = 0; dy < 3; ++dy) {
        int yy = y + dy - 1;
        if (yy < 0 || yy > 127) continue;
        #pragma unroll
        for (int dx = 0; dx < 3; ++dx) {
            int xx = x + dx - 1;
            if (xx < 0 || xx > 127) continue;
            int nn = yy * WW + xx;
            a1 = fmaf(bf2f(t1[nn]), w1[dy * 3 + dx], a1);
            a2 = fmaf(bf2f(t2[nn]), w2[dy * 3 + dx], a2);
        }
    }
    float ge = 0.5f * a1 * (1.f + erff(a1 * 0.70710678118654752f));
    g[(size_t)c * NN + n] = f2bf(ge * a2);
}

extern "C" void kernel_launch(void* const* d_in, const int* in_sizes, int n_in,
                              void* d_out, int out_size, void* d_ws, size_t ws_size,
                              hipStream_t stream)
{
    const float* x      = (const float*)d_in[0];
    const float* ln1_w  = (const float*)d_in[1];
    const float* ln2_w  = (const float*)d_in[2];
    const float* qkv_w  = (const float*)d_in[3];
    const float* off_w  = (const float*)d_in[4];
    const float* rpb    = (const float*)d_in[5];
    const float* proj_w = (const float*)d_in[6];
    const float* pi_w   = (const float*)d_in[7];
    const float* dw_w   = (const float*)d_in[8];
    const float* po_w   = (const float*)d_in[9];
    float* out = (float*)d_out;

    // ---- workspace layout (bytes), total ~59 MB ----
    char* ws = (char*)d_ws;
    ushort_t* qkv_wb  = (ushort_t*)ws;                       // 576*192
    ushort_t* off_wb  = qkv_wb  + 576 * 192;                 // 72*192
    ushort_t* proj_wb = off_wb  + 72 * 192;                  // 192*192
    ushort_t* pi_wb   = proj_wb + 192 * 192;                 // 1020*192
    ushort_t* po_wb   = pi_wb   + 1020 * 192;                // 192*512
    ushort_t* xn      = po_wb   + 192 * 512;                 // 192*N   (also attn-out, xn2)
    ushort_t* qkvb    = xn      + (size_t)CDIM * NN;         // 576*N   (also g [512*N])
    ushort_t* offb    = qkvb    + (size_t)3 * CDIM * NN;     // 72*N
    ushort_t* t       = offb    + (size_t)72 * NN;           // 1020*N
    ushort_t* attn    = xn;
    ushort_t* g       = qkvb;

    dim3 blk(256);

    // weight conversions (once per call)
    convw_kernel<<<dim3((576 * 192 + 255) / 256), blk, 0, stream>>>(qkv_w,  qkv_wb,  576, 192, 192);
    convw_kernel<<<dim3((72 * 192 + 255) / 256),  blk, 0, stream>>>(off_w,  off_wb,  72,  192, 192);
    convw_kernel<<<dim3((192 * 192 + 255) / 256), blk, 0, stream>>>(proj_w, proj_wb, 192, 192, 192);
    convw_kernel<<<dim3((1020 * 192 + 255) / 256),blk, 0, stream>>>(pi_w,   pi_wb,   1020,192, 192);
    convw_kernel<<<dim3((192 * 512 + 255) / 256), blk, 0, stream>>>(po_w,   po_wb,   192, 510, 512);

    const int shm192 = 64 * (192 + 8) * 2;   // 25600 B
    const int shm512 = 64 * (512 + 8) * 2;   // 66560 B

    for (int b = 0; b < BB; ++b) {
        const float* xb   = x   + (size_t)b * CDIM * NN;
        float*       outb = out + (size_t)b * CDIM * NN;

        // 1. xn1 = LN1(x)
        ln_kernel<<<dim3(NN / 256), blk, 0, stream>>>(xb, ln1_w, xn);
        // 2. qkv = qkv_wb @ xn1  (bf16)
        gemm_mfma<0><<<dim3(NN / 64, 3), blk, shm192, stream>>>(
            qkv_wb, xn, nullptr, qkvb, 576, 192, 200);
        // 3. off = off_wb @ xn1  (bf16)
        gemm_mfma<0><<<dim3(NN / 64, 1), blk, shm192, stream>>>(
            off_wb, xn, nullptr, offb, 72, 192, 200);
        // 4. deformable attention (attn aliases xn)
        attn_kernel<<<dim3(NHEADS * NN * 4 / 256), blk, 0, stream>>>(qkvb, offb, rpb, attn);
        // 5. x1 = x + proj_wb @ attn  -> d_out (f32)
        gemm_mfma<2><<<dim3(NN / 64, 1), blk, shm192, stream>>>(
            proj_wb, attn, xb, outb, 192, 192, 200);
        // 6. xn2 = LN2(x1)
        ln_kernel<<<dim3(NN / 256), blk, 0, stream>>>(outb, ln2_w, xn);
        // 7. t = pi_wb @ xn2  (bf16)
        gemm_mfma<0><<<dim3(NN / 64, 4), blk, shm192, stream>>>(
            pi_wb, xn, nullptr, t, 1020, 192, 200);
        // 8. g = gelu(dw(t1)) * dw(t2)  (512-ch padded; aliases qkvb)
        dwgate_kernel<<<dim3(512 * NN / 256), blk, 0, stream>>>(t, dw_w, g);
        // 9. out = x1 + po_wb @ g  (in-place residual on d_out)
        gemm_mfma<2><<<dim3(NN / 64, 1), blk, shm512, stream>>>(
            po_wb, g, outb, outb, 192, 512, 520);
    }
}

// Round 4
// 626.249 us; speedup vs baseline: 1.8801x; 1.4553x over previous
//
#include <hip/hip_runtime.h>
#include <math.h>

#define NN 16384      // H*W per image
#define WW 128
#define CDIM 192
#define HIDD 510
#define BB 2

typedef unsigned short ushort_t;
using short8 = __attribute__((ext_vector_type(8))) short;
using f32x4  = __attribute__((ext_vector_type(4))) float;

__device__ __forceinline__ float bf2f(ushort_t u) {
    union { unsigned int i; float f; } v; v.i = ((unsigned int)u) << 16; return v.f;
}
__device__ __forceinline__ ushort_t f2bf(float f) {
    union { unsigned int i; float f; } v; v.f = f;
    unsigned int i = v.i;
    return (ushort_t)((i + 0x7fffu + ((i >> 16) & 1u)) >> 16);  // RNE
}

// ---------------- weight f32 -> bf16 (with K padding) ----------------
__global__ __launch_bounds__(256) void convw_kernel(const float* __restrict__ src,
                                                    ushort_t* __restrict__ dst,
                                                    int O, int Kin, int Kout) {
    int idx = blockIdx.x * 256 + threadIdx.x;
    if (idx >= O * Kout) return;
    int o = idx / Kout, k = idx - o * Kout;
    dst[idx] = (k < Kin) ? f2bf(src[(size_t)o * Kin + k]) : (ushort_t)0;
}

// ------------- BiasFree LayerNorm; out pixel-major [N][192] bf16 -----------
__global__ __launch_bounds__(256) void ln_kernel(const float* __restrict__ x,
                                                 const float* __restrict__ w,
                                                 ushort_t* __restrict__ y) {
    int n = blockIdx.x * 256 + threadIdx.x;   // over N
    const float* xp = x + n;
    float s = 0.f, s2 = 0.f;
    for (int c = 0; c < CDIM; ++c) {
        float v = xp[(size_t)c * NN];
        s += v; s2 += v * v;
    }
    const float inv = 1.f / (float)CDIM;
    float mu  = s * inv;
    float var = s2 * inv - mu * mu;
    float rs  = rsqrtf(var + 1e-5f);
    ushort_t* yp = y + (size_t)n * CDIM;
    for (int c0 = 0; c0 < CDIM; c0 += 8) {
        short8 o8;
        #pragma unroll
        for (int j = 0; j < 8; ++j)
            o8[j] = (short)f2bf(xp[(size_t)(c0 + j) * NN] * rs * w[c0 + j]);
        *(short8*)(yp + c0) = o8;
    }
}

// ---------------- MFMA GEMM: acc[o,n] = sum_k Wb[o,k]*X_pm[n,k] ------------
// X pixel-major [N][K] bf16 (K = LDX). Block: 64 n, 256 o (4 waves x 64 o).
// MODE 0: bf16 out at ((o/48)*NN+n)*48 + o%48      (qkv planes)
// MODE 1: bf16 out at ((o/18)*NN+n)*24 + o%18      (offsets, scalar)
// MODE 2: f32  out at o*NN+n, += R                 (proj / po epilogues)
// MODE 3: bf16 out at n*1024 + o                   (pi -> t)
template<int MODE>
__global__ __launch_bounds__(256) void gemm_mfma(
    const ushort_t* __restrict__ Wb,
    const ushort_t* __restrict__ X,
    const float* __restrict__ R,
    void* __restrict__ Yv,
    int O, int K, int KP)
{
    extern __shared__ ushort_t Xt[];   // [64][KP]
    int tid = threadIdx.x;
    int n0 = blockIdx.x * 64;

    // ---- stage X tile: direct vectorized row copy ----
    {
        int r = tid & 63;
        const ushort_t* src = X + (size_t)(n0 + r) * K;
        int nseg = K >> 3;
        for (int sseg = tid >> 6; sseg < nseg; sseg += 4)
            *(uint4*)&Xt[(size_t)r * KP + sseg * 8] = *(const uint4*)(src + sseg * 8);
    }
    __syncthreads();

    int w = tid >> 6, l = tid & 63;
    int o0w = blockIdx.y * 256 + w * 64;
    if (o0w >= O) return;

    int lrow = l & 15;
    int lk   = (l >> 4) * 8;

    f32x4 acc[4][4] = {};

    for (int kk0 = 0; kk0 < K; kk0 += 32) {
        short8 bfr[4];
        #pragma unroll
        for (int ni = 0; ni < 4; ++ni)
            bfr[ni] = *(const short8*)&Xt[(size_t)(ni * 16 + lrow) * KP + kk0 + lk];
        short8 afr[4];
        #pragma unroll
        for (int mi = 0; mi < 4; ++mi) {
            int orow = o0w + mi * 16 + lrow;
            if (orow < O)
                afr[mi] = *(const short8*)(Wb + (size_t)orow * K + kk0 + lk);
            else
                afr[mi] = short8{0,0,0,0,0,0,0,0};
        }
        #pragma unroll
        for (int mi = 0; mi < 4; ++mi)
            #pragma unroll
            for (int ni = 0; ni < 4; ++ni)
                acc[mi][ni] = __builtin_amdgcn_mfma_f32_16x16x32_bf16(
                    afr[mi], bfr[ni], acc[mi][ni], 0, 0, 0);
    }

    // ---- epilogue: D col(lane&15)=n, row=(lane>>4)*4+r = o ----
    int orow0 = (l >> 4) * 4;
    #pragma unroll
    for (int mi = 0; mi < 4; ++mi) {
        #pragma unroll
        for (int ni = 0; ni < 4; ++ni) {
            int n = n0 + ni * 16 + lrow;
            int obase = o0w + mi * 16 + orow0;
            float v0 = acc[mi][ni][0], v1 = acc[mi][ni][1];
            float v2 = acc[mi][ni][2], v3 = acc[mi][ni][3];
            if (MODE == 0 || MODE == 3) {
                if (obase >= O) continue;   // O multiple of 4; groups aligned
                unsigned int lo = (unsigned int)f2bf(v0) | ((unsigned int)f2bf(v1) << 16);
                unsigned int hi = (unsigned int)f2bf(v2) | ((unsigned int)f2bf(v3) << 16);
                size_t base = (MODE == 0)
                    ? ((size_t)(obase / 48) * NN + n) * 48 + (obase % 48)
                    : (size_t)n * 1024 + obase;
                *(uint2*)((ushort_t*)Yv + base) = make_uint2(lo, hi);
            } else if (MODE == 1) {
                float vv[4] = {v0, v1, v2, v3};
                #pragma unroll
                for (int r = 0; r < 4; ++r) {
                    int o = obase + r;
                    if (o < O)
                        ((ushort_t*)Yv)[((size_t)(o / 18) * NN + n) * 24 + (o % 18)] = f2bf(vv[r]);
                }
            } else {  // MODE 2
                float vv[4] = {v0, v1, v2, v3};
                #pragma unroll
                for (int r = 0; r < 4; ++r) {
                    int o = obase + r;
                    if (o < O) {
                        size_t idx = (size_t)o * NN + n;
                        ((float*)Yv)[idx] = vv[r] + R[idx];
                    }
                }
            }
        }
    }
}

// ------------- deformable attention, pixel-major, 2-lane split -------------
// qkv_pm: [12][N][48]  planes: q=h, k=4+h, v=8+h
// off_pm: [4][N][24]   (cols 0..17 valid: kpt*2 + {y,x})
// out_pm: [N][192]     col = h*48 + c
__global__ __launch_bounds__(256) void attn_kernel(
    const ushort_t* __restrict__ qkv_pm,
    const ushort_t* __restrict__ off_pm,
    const float* __restrict__ rpb,     // [4,9]
    ushort_t* __restrict__ out_pm)
{
    int idx = blockIdx.x * 256 + threadIdx.x;  // over 2*4*N
    int s   = idx & 1;
    int pix = idx >> 1;
    int n   = pix & (NN - 1);
    int h   = pix >> 14;
    int py = n >> 7, px = n & 127;

    // ---- offsets: contiguous 48B row ----
    union { uint4 u[3]; ushort_t v[24]; } ob;
    {
        const ushort_t* op = off_pm + ((size_t)h * NN + n) * 24;
        ob.u[0] = *(const uint4*)op;
        ob.u[1] = *(const uint4*)(op + 8);
        ob.u[2] = *(const uint4*)(op + 16);
    }

    float wgt[9][4];
    int   ofs[9][4];
    #pragma unroll
    for (int kpt = 0; kpt < 9; ++kpt) {
        float oy = bf2f(ob.v[kpt * 2 + 0]);
        float ox = bf2f(ob.v[kpt * 2 + 1]);
        float cy = fminf(fmaxf((float)(py + (kpt / 3) - 1) + oy, 0.f), 127.f);
        float cx = fminf(fmaxf((float)(px + (kpt % 3) - 1) + ox, 0.f), 127.f);
        float y0f = floorf(cy), x0f = floorf(cx);
        float wy = cy - y0f, wx = cx - x0f;
        int y0 = (int)y0f, x0 = (int)x0f;
        int y1 = min(y0 + 1, 127), x1 = min(x0 + 1, 127);
        ofs[kpt][0] = y0 * WW + x0;  wgt[kpt][0] = (1.f - wy) * (1.f - wx);
        ofs[kpt][1] = y0 * WW + x1;  wgt[kpt][1] = (1.f - wy) * wx;
        ofs[kpt][2] = y1 * WW + x0;  wgt[kpt][2] = wy * (1.f - wx);
        ofs[kpt][3] = y1 * WW + x1;  wgt[kpt][3] = wy * wx;
    }

    const ushort_t* qrow  = qkv_pm + ((size_t)h * NN + n) * 48;
    const ushort_t* kbase = qkv_pm + ((size_t)(4 + h) * NN) * 48;
    const ushort_t* vbase = qkv_pm + ((size_t)(8 + h) * NN) * 48;

    // ---- K phase: partial dots over this lane's 3 chunks (24 ch) ----
    float logits[9] = {};
    for (int ch = s * 3; ch < s * 3 + 3; ++ch) {
        int co = ch * 8;
        short8 q8 = *(const short8*)(qrow + co);
        float qf[8];
        #pragma unroll
        for (int j = 0; j < 8; ++j) qf[j] = bf2f((ushort_t)q8[j]);
        #pragma unroll
        for (int kpt = 0; kpt < 9; ++kpt) {
            short8 k0 = *(const short8*)(kbase + (size_t)ofs[kpt][0] * 48 + co);
            short8 k1 = *(const short8*)(kbase + (size_t)ofs[kpt][1] * 48 + co);
            short8 k2 = *(const short8*)(kbase + (size_t)ofs[kpt][2] * 48 + co);
            short8 k3 = *(const short8*)(kbase + (size_t)ofs[kpt][3] * 48 + co);
            float w0 = wgt[kpt][0], w1 = wgt[kpt][1], w2 = wgt[kpt][2], w3 = wgt[kpt][3];
            float acc = 0.f;
            #pragma unroll
            for (int j = 0; j < 8; ++j) {
                float ks = w0 * bf2f((ushort_t)k0[j]);
                ks = fmaf(w1, bf2f((ushort_t)k1[j]), ks);
                ks = fmaf(w2, bf2f((ushort_t)k2[j]), ks);
                ks = fmaf(w3, bf2f((ushort_t)k3[j]), ks);
                acc = fmaf(qf[j], ks, acc);
            }
            logits[kpt] += acc;
        }
    }
    // ---- reduce across lane pair, softmax ----
    #pragma unroll
    for (int kpt = 0; kpt < 9; ++kpt) {
        float v = logits[kpt] + __shfl_xor(logits[kpt], 1);
        logits[kpt] = v * 0.14433756729740643f + rpb[h * 9 + kpt];
    }
    float m = logits[0];
    #pragma unroll
    for (int i = 1; i < 9; ++i) m = fmaxf(m, logits[i]);
    float aw[9]; float ssum = 0.f;
    #pragma unroll
    for (int i = 0; i < 9; ++i) { aw[i] = __expf(logits[i] - m); ssum += aw[i]; }
    float inv = 1.f / ssum;
    #pragma unroll
    for (int i = 0; i < 9; ++i) aw[i] *= inv;

    // ---- V phase: this lane's 3 output chunks ----
    ushort_t* orow = out_pm + (size_t)n * CDIM + h * 48;
    for (int ch = s * 3; ch < s * 3 + 3; ++ch) {
        int co = ch * 8;
        float acc[8] = {};
        #pragma unroll
        for (int kpt = 0; kpt < 9; ++kpt) {
            short8 v0 = *(const short8*)(vbase + (size_t)ofs[kpt][0] * 48 + co);
            short8 v1 = *(const short8*)(vbase + (size_t)ofs[kpt][1] * 48 + co);
            short8 v2 = *(const short8*)(vbase + (size_t)ofs[kpt][2] * 48 + co);
            short8 v3 = *(const short8*)(vbase + (size_t)ofs[kpt][3] * 48 + co);
            float w0 = wgt[kpt][0], w1 = wgt[kpt][1], w2 = wgt[kpt][2], w3 = wgt[kpt][3];
            float a = aw[kpt];
            #pragma unroll
            for (int j = 0; j < 8; ++j) {
                float vs = w0 * bf2f((ushort_t)v0[j]);
                vs = fmaf(w1, bf2f((ushort_t)v1[j]), vs);
                vs = fmaf(w2, bf2f((ushort_t)v2[j]), vs);
                vs = fmaf(w3, bf2f((ushort_t)v3[j]), vs);
                acc[j] = fmaf(a, vs, acc[j]);
            }
        }
        short8 o8;
        #pragma unroll
        for (int j = 0; j < 8; ++j) o8[j] = (short)f2bf(acc[j]);
        *(short8*)(orow + co) = o8;
    }
}

// ------- depthwise 3x3 (both halves) + exact-GELU gate; pixel-major --------
// t_pm [N][1024] (cols 0..1019 valid), g_pm [N][512] (cols 510/511 = 0)
__global__ __launch_bounds__(256) void dwgate_kernel(
    const ushort_t* __restrict__ t_pm,
    const float* __restrict__ dww,    // [1020, 9]
    ushort_t* __restrict__ g_pm)
{
    int idx = blockIdx.x * 256 + threadIdx.x;  // over N*512
    int c = idx & 511;
    int n = idx >> 9;
    if (c >= HIDD) { g_pm[(size_t)n * 512 + c] = 0; return; }
    int y = n >> 7, x = n & 127;
    const float* w1 = dww + c * 9;
    const float* w2 = dww + (c + HIDD) * 9;
    float a1 = 0.f, a2 = 0.f;
    #pragma unroll
    for (int dy = 0; dy < 3; ++dy) {
        int yy = y + dy - 1;
        if (yy < 0 || yy > 127) continue;
        #pragma unroll
        for (int dx = 0; dx < 3; ++dx) {
            int xx = x + dx - 1;
            if (xx < 0 || xx > 127) continue;
            const ushort_t* tr = t_pm + (size_t)(yy * WW + xx) * 1024;
            a1 = fmaf(bf2f(tr[c]),        w1[dy * 3 + dx], a1);
            a2 = fmaf(bf2f(tr[c + HIDD]), w2[dy * 3 + dx], a2);
        }
    }
    float ge = 0.5f * a1 * (1.f + erff(a1 * 0.70710678118654752f));
    g_pm[(size_t)n * 512 + c] = f2bf(ge * a2);
}

extern "C" void kernel_launch(void* const* d_in, const int* in_sizes, int n_in,
                              void* d_out, int out_size, void* d_ws, size_t ws_size,
                              hipStream_t stream)
{
    const float* x      = (const float*)d_in[0];
    const float* ln1_w  = (const float*)d_in[1];
    const float* ln2_w  = (const float*)d_in[2];
    const float* qkv_w  = (const float*)d_in[3];
    const float* off_w  = (const float*)d_in[4];
    const float* rpb    = (const float*)d_in[5];
    const float* proj_w = (const float*)d_in[6];
    const float* pi_w   = (const float*)d_in[7];
    const float* dw_w   = (const float*)d_in[8];
    const float* po_w   = (const float*)d_in[9];
    float* out = (float*)d_out;

    // ---- workspace layout (ushort units), total ~63 MB ----
    ushort_t* ws = (ushort_t*)d_ws;
    ushort_t* qkv_wb  = ws;                                  // 576*192
    ushort_t* off_wb  = qkv_wb  + 576 * 192;                 // 72*192
    ushort_t* proj_wb = off_wb  + 72 * 192;                  // 192*192
    ushort_t* pi_wb   = proj_wb + 192 * 192;                 // 1020*192
    ushort_t* po_wb   = pi_wb   + 1020 * 192;                // 192*512
    ushort_t* xn      = po_wb   + 192 * 512;                 // [N][192]  (also attn-out, xn2)
    ushort_t* qkvb    = xn      + (size_t)NN * CDIM;         // [12][N][48] (also g_pm [N][512])
    ushort_t* offb    = qkvb    + (size_t)12 * NN * 48;      // [4][N][24]
    ushort_t* t       = offb    + (size_t)4 * NN * 24;       // [N][1024]
    ushort_t* attn    = xn;
    ushort_t* g       = qkvb;

    dim3 blk(256);

    // weight conversions (once per call)
    convw_kernel<<<dim3((576 * 192 + 255) / 256), blk, 0, stream>>>(qkv_w,  qkv_wb,  576, 192, 192);
    convw_kernel<<<dim3((72 * 192 + 255) / 256),  blk, 0, stream>>>(off_w,  off_wb,  72,  192, 192);
    convw_kernel<<<dim3((192 * 192 + 255) / 256), blk, 0, stream>>>(proj_w, proj_wb, 192, 192, 192);
    convw_kernel<<<dim3((1020 * 192 + 255) / 256),blk, 0, stream>>>(pi_w,   pi_wb,   1020,192, 192);
    convw_kernel<<<dim3((192 * 512 + 255) / 256), blk, 0, stream>>>(po_w,   po_wb,   192, 510, 512);

    const int shm192 = 64 * (192 + 8) * 2;   // 25600 B
    const int shm512 = 64 * (512 + 8) * 2;   // 66560 B

    for (int b = 0; b < BB; ++b) {
        const float* xb   = x   + (size_t)b * CDIM * NN;
        float*       outb = out + (size_t)b * CDIM * NN;

        // 1. xn1 = LN1(x)        (pixel-major bf16)
        ln_kernel<<<dim3(NN / 256), blk, 0, stream>>>(xb, ln1_w, xn);
        // 2. qkv planes = qkv_wb @ xn1
        gemm_mfma<0><<<dim3(NN / 64, 3), blk, shm192, stream>>>(
            qkv_wb, xn, nullptr, qkvb, 576, 192, 200);
        // 3. offsets = off_wb @ xn1
        gemm_mfma<1><<<dim3(NN / 64, 1), blk, shm192, stream>>>(
            off_wb, xn, nullptr, offb, 72, 192, 200);
        // 4. deformable attention (out aliases xn)
        attn_kernel<<<dim3(2 * 4 * NN / 256), blk, 0, stream>>>(qkvb, offb, rpb, attn);
        // 5. x1 = x + proj_wb @ attn  -> d_out (f32 channel-major)
        gemm_mfma<2><<<dim3(NN / 64, 1), blk, shm192, stream>>>(
            proj_wb, attn, xb, outb, 192, 192, 200);
        // 6. xn2 = LN2(x1)
        ln_kernel<<<dim3(NN / 256), blk, 0, stream>>>(outb, ln2_w, xn);
        // 7. t = pi_wb @ xn2   ([N][1024])
        gemm_mfma<3><<<dim3(NN / 64, 4), blk, shm192, stream>>>(
            pi_wb, xn, nullptr, t, 1020, 192, 200);
        // 8. g = gelu(dw(t1)) * dw(t2)   ([N][512], aliases qkvb)
        dwgate_kernel<<<dim3(NN * 512 / 256), blk, 0, stream>>>(t, dw_w, g);
        // 9. out = x1 + po_wb @ g   (in-place residual on d_out)
        gemm_mfma<2><<<dim3(NN / 64, 1), blk, shm512, stream>>>(
            po_wb, g, outb, outb, 192, 512, 520);
    }
}

// Round 5
// 419.491 us; speedup vs baseline: 2.8068x; 1.4929x over previous
//
#include <hip/hip_runtime.h>
#include <math.h>

#define NN 16384      // H*W per image
#define WW 128
#define CDIM 192
#define HIDD 510
#define BB 2

typedef unsigned short ushort_t;
using short8 = __attribute__((ext_vector_type(8))) short;
using f32x4  = __attribute__((ext_vector_type(4))) float;

__device__ __forceinline__ float bf2f(ushort_t u) {
    union { unsigned int i; float f; } v; v.i = ((unsigned int)u) << 16; return v.f;
}
__device__ __forceinline__ ushort_t f2bf(float f) {
    union { unsigned int i; float f; } v; v.f = f;
    unsigned int i = v.i;
    return (ushort_t)((i + 0x7fffu + ((i >> 16) & 1u)) >> 16);  // RNE
}

// ---------------- weight f32 -> bf16 (with K padding) ----------------
__global__ __launch_bounds__(256) void convw_kernel(const float* __restrict__ src,
                                                    ushort_t* __restrict__ dst,
                                                    int O, int Kin, int Kout) {
    int idx = blockIdx.x * 256 + threadIdx.x;
    if (idx >= O * Kout) return;
    int o = idx / Kout, k = idx - o * Kout;
    dst[idx] = (k < Kin) ? f2bf(src[(size_t)o * Kin + k]) : (ushort_t)0;
}

// ---- pi weight rows remapped: out row o' -> src row o'-2 for o'>=512;
//      rows 510,511,1022,1023 are zero. Gives t layout [N][{512|512}]. ----
__global__ __launch_bounds__(256) void convw_pi_kernel(const float* __restrict__ src,
                                                       ushort_t* __restrict__ dst) {
    int idx = blockIdx.x * 256 + threadIdx.x;   // 1024*192
    if (idx >= 1024 * 192) return;
    int o = idx / 192, k = idx - o * 192;
    bool zero = (o == 510) || (o == 511) || (o >= 1022);
    int so = (o < 510) ? o : o - 2;
    dst[idx] = zero ? (ushort_t)0 : f2bf(src[(size_t)so * 192 + k]);
}

// ---- dw weights [1020][9] f32 -> [9][2][512] bf16 (position-major) ----
__global__ __launch_bounds__(256) void convw_dw_kernel(const float* __restrict__ src,
                                                       ushort_t* __restrict__ dst) {
    int idx = blockIdx.x * 256 + threadIdx.x;   // 9*1024
    if (idx >= 9 * 1024) return;
    int p = idx >> 10, c = idx & 1023;
    int half = c >> 9, cc = c & 511;
    dst[idx] = (cc < HIDD) ? f2bf(src[(size_t)(half * HIDD + cc) * 9 + p]) : (ushort_t)0;
}

// ------------- BiasFree LayerNorm; out pixel-major [N][192] bf16 -----------
__global__ __launch_bounds__(256) void ln_kernel(const float* __restrict__ x,
                                                 const float* __restrict__ w,
                                                 ushort_t* __restrict__ y) {
    int n = blockIdx.x * 256 + threadIdx.x;   // over N
    const float* xp = x + n;
    float s = 0.f, s2 = 0.f;
    for (int c = 0; c < CDIM; ++c) {
        float v = xp[(size_t)c * NN];
        s += v; s2 += v * v;
    }
    const float inv = 1.f / (float)CDIM;
    float mu  = s * inv;
    float var = s2 * inv - mu * mu;
    float rs  = rsqrtf(var + 1e-5f);
    ushort_t* yp = y + (size_t)n * CDIM;
    for (int c0 = 0; c0 < CDIM; c0 += 8) {
        short8 o8;
        #pragma unroll
        for (int j = 0; j < 8; ++j)
            o8[j] = (short)f2bf(xp[(size_t)(c0 + j) * NN] * rs * w[c0 + j]);
        *(short8*)(yp + c0) = o8;
    }
}

// ---------------- MFMA GEMM: acc[o,n] = sum_k Wb[o,k]*X_pm[n,k] ------------
// X pixel-major [N][K] bf16. Block: 64 n, 256 o (4 waves x 64 o).
// MODE 0: bf16 out at ((o/48)*NN+n)*48 + o%48      (qkv planes)
// MODE 1: bf16 out at ((o/18)*NN+n)*24 + o%18      (offsets, scalar)
// MODE 2: f32  out at o*NN+n, += R                 (proj / po epilogues)
// MODE 3: bf16 out at n*1024 + o                   (pi -> t)
template<int MODE>
__global__ __launch_bounds__(256) void gemm_mfma(
    const ushort_t* __restrict__ Wb,
    const ushort_t* __restrict__ X,
    const float* __restrict__ R,
    void* __restrict__ Yv,
    int O, int K, int KP)
{
    extern __shared__ ushort_t Xt[];   // [64][KP]
    int tid = threadIdx.x;
    int n0 = blockIdx.x * 64;

    // ---- stage X tile: direct vectorized row copy ----
    {
        int r = tid & 63;
        const ushort_t* src = X + (size_t)(n0 + r) * K;
        int nseg = K >> 3;
        for (int sseg = tid >> 6; sseg < nseg; sseg += 4)
            *(uint4*)&Xt[(size_t)r * KP + sseg * 8] = *(const uint4*)(src + sseg * 8);
    }
    __syncthreads();

    int w = tid >> 6, l = tid & 63;
    int o0w = blockIdx.y * 256 + w * 64;
    if (o0w >= O) return;

    int lrow = l & 15;
    int lk   = (l >> 4) * 8;

    f32x4 acc[4][4] = {};

    for (int kk0 = 0; kk0 < K; kk0 += 32) {
        short8 bfr[4];
        #pragma unroll
        for (int ni = 0; ni < 4; ++ni)
            bfr[ni] = *(const short8*)&Xt[(size_t)(ni * 16 + lrow) * KP + kk0 + lk];
        short8 afr[4];
        #pragma unroll
        for (int mi = 0; mi < 4; ++mi) {
            int orow = o0w + mi * 16 + lrow;
            if (orow < O)
                afr[mi] = *(const short8*)(Wb + (size_t)orow * K + kk0 + lk);
            else
                afr[mi] = short8{0,0,0,0,0,0,0,0};
        }
        #pragma unroll
        for (int mi = 0; mi < 4; ++mi)
            #pragma unroll
            for (int ni = 0; ni < 4; ++ni)
                acc[mi][ni] = __builtin_amdgcn_mfma_f32_16x16x32_bf16(
                    afr[mi], bfr[ni], acc[mi][ni], 0, 0, 0);
    }

    // ---- epilogue: D col(lane&15)=n, row=(lane>>4)*4+r = o ----
    int orow0 = (l >> 4) * 4;
    #pragma unroll
    for (int mi = 0; mi < 4; ++mi) {
        #pragma unroll
        for (int ni = 0; ni < 4; ++ni) {
            int n = n0 + ni * 16 + lrow;
            int obase = o0w + mi * 16 + orow0;
            float v0 = acc[mi][ni][0], v1 = acc[mi][ni][1];
            float v2 = acc[mi][ni][2], v3 = acc[mi][ni][3];
            if (MODE == 0 || MODE == 3) {
                if (obase >= O) continue;   // O multiple of 4; groups aligned
                unsigned int lo = (unsigned int)f2bf(v0) | ((unsigned int)f2bf(v1) << 16);
                unsigned int hi = (unsigned int)f2bf(v2) | ((unsigned int)f2bf(v3) << 16);
                size_t base = (MODE == 0)
                    ? ((size_t)(obase / 48) * NN + n) * 48 + (obase % 48)
                    : (size_t)n * 1024 + obase;
                *(uint2*)((ushort_t*)Yv + base) = make_uint2(lo, hi);
            } else if (MODE == 1) {
                float vv[4] = {v0, v1, v2, v3};
                #pragma unroll
                for (int r = 0; r < 4; ++r) {
                    int o = obase + r;
                    if (o < O)
                        ((ushort_t*)Yv)[((size_t)(o / 18) * NN + n) * 24 + (o % 18)] = f2bf(vv[r]);
                }
            } else {  // MODE 2
                float vv[4] = {v0, v1, v2, v3};
                #pragma unroll
                for (int r = 0; r < 4; ++r) {
                    int o = obase + r;
                    if (o < O) {
                        size_t idx = (size_t)o * NN + n;
                        ((float*)Yv)[idx] = vv[r] + R[idx];
                    }
                }
            }
        }
    }
}

// ------------- deformable attention, pixel-major, 2-lane split -------------
// qkv_pm: [12][N][48]  planes: q=h, k=4+h, v=8+h
// off_pm: [4][N][24]   (cols 0..17 valid: kpt*2 + {y,x})
// out_pm: [N][192]     col = h*48 + c
__global__ __launch_bounds__(256) void attn_kernel(
    const ushort_t* __restrict__ qkv_pm,
    const ushort_t* __restrict__ off_pm,
    const float* __restrict__ rpb,     // [4,9]
    ushort_t* __restrict__ out_pm)
{
    int idx = blockIdx.x * 256 + threadIdx.x;  // over 2*4*N
    int s   = idx & 1;
    int pix = idx >> 1;
    int n   = pix & (NN - 1);
    int h   = pix >> 14;
    int py = n >> 7, px = n & 127;

    // ---- offsets: contiguous 48B row ----
    union { uint4 u[3]; ushort_t v[24]; } ob;
    {
        const ushort_t* op = off_pm + ((size_t)h * NN + n) * 24;
        ob.u[0] = *(const uint4*)op;
        ob.u[1] = *(const uint4*)(op + 8);
        ob.u[2] = *(const uint4*)(op + 16);
    }

    float wgt[9][4];
    int   ofs[9][4];
    #pragma unroll
    for (int kpt = 0; kpt < 9; ++kpt) {
        float oy = bf2f(ob.v[kpt * 2 + 0]);
        float ox = bf2f(ob.v[kpt * 2 + 1]);
        float cy = fminf(fmaxf((float)(py + (kpt / 3) - 1) + oy, 0.f), 127.f);
        float cx = fminf(fmaxf((float)(px + (kpt % 3) - 1) + ox, 0.f), 127.f);
        float y0f = floorf(cy), x0f = floorf(cx);
        float wy = cy - y0f, wx = cx - x0f;
        int y0 = (int)y0f, x0 = (int)x0f;
        int y1 = min(y0 + 1, 127), x1 = min(x0 + 1, 127);
        ofs[kpt][0] = y0 * WW + x0;  wgt[kpt][0] = (1.f - wy) * (1.f - wx);
        ofs[kpt][1] = y0 * WW + x1;  wgt[kpt][1] = (1.f - wy) * wx;
        ofs[kpt][2] = y1 * WW + x0;  wgt[kpt][2] = wy * (1.f - wx);
        ofs[kpt][3] = y1 * WW + x1;  wgt[kpt][3] = wy * wx;
    }

    const ushort_t* qrow  = qkv_pm + ((size_t)h * NN + n) * 48;
    const ushort_t* kbase = qkv_pm + ((size_t)(4 + h) * NN) * 48;
    const ushort_t* vbase = qkv_pm + ((size_t)(8 + h) * NN) * 48;

    // ---- K phase: partial dots over this lane's 3 chunks (24 ch) ----
    float logits[9] = {};
    for (int ch = s * 3; ch < s * 3 + 3; ++ch) {
        int co = ch * 8;
        short8 q8 = *(const short8*)(qrow + co);
        float qf[8];
        #pragma unroll
        for (int j = 0; j < 8; ++j) qf[j] = bf2f((ushort_t)q8[j]);
        #pragma unroll
        for (int kpt = 0; kpt < 9; ++kpt) {
            short8 k0 = *(const short8*)(kbase + (size_t)ofs[kpt][0] * 48 + co);
            short8 k1 = *(const short8*)(kbase + (size_t)ofs[kpt][1] * 48 + co);
            short8 k2 = *(const short8*)(kbase + (size_t)ofs[kpt][2] * 48 + co);
            short8 k3 = *(const short8*)(kbase + (size_t)ofs[kpt][3] * 48 + co);
            float w0 = wgt[kpt][0], w1 = wgt[kpt][1], w2 = wgt[kpt][2], w3 = wgt[kpt][3];
            float acc = 0.f;
            #pragma unroll
            for (int j = 0; j < 8; ++j) {
                float ks = w0 * bf2f((ushort_t)k0[j]);
                ks = fmaf(w1, bf2f((ushort_t)k1[j]), ks);
                ks = fmaf(w2, bf2f((ushort_t)k2[j]), ks);
                ks = fmaf(w3, bf2f((ushort_t)k3[j]), ks);
                acc = fmaf(qf[j], ks, acc);
            }
            logits[kpt] += acc;
        }
    }
    // ---- reduce across lane pair, softmax ----
    #pragma unroll
    for (int kpt = 0; kpt < 9; ++kpt) {
        float v = logits[kpt] + __shfl_xor(logits[kpt], 1);
        logits[kpt] = v * 0.14433756729740643f + rpb[h * 9 + kpt];
    }
    float m = logits[0];
    #pragma unroll
    for (int i = 1; i < 9; ++i) m = fmaxf(m, logits[i]);
    float aw[9]; float ssum = 0.f;
    #pragma unroll
    for (int i = 0; i < 9; ++i) { aw[i] = __expf(logits[i] - m); ssum += aw[i]; }
    float inv = 1.f / ssum;
    #pragma unroll
    for (int i = 0; i < 9; ++i) aw[i] *= inv;

    // ---- V phase: this lane's 3 output chunks ----
    ushort_t* orow = out_pm + (size_t)n * CDIM + h * 48;
    for (int ch = s * 3; ch < s * 3 + 3; ++ch) {
        int co = ch * 8;
        float acc[8] = {};
        #pragma unroll
        for (int kpt = 0; kpt < 9; ++kpt) {
            short8 v0 = *(const short8*)(vbase + (size_t)ofs[kpt][0] * 48 + co);
            short8 v1 = *(const short8*)(vbase + (size_t)ofs[kpt][1] * 48 + co);
            short8 v2 = *(const short8*)(vbase + (size_t)ofs[kpt][2] * 48 + co);
            short8 v3 = *(const short8*)(vbase + (size_t)ofs[kpt][3] * 48 + co);
            float w0 = wgt[kpt][0], w1 = wgt[kpt][1], w2 = wgt[kpt][2], w3 = wgt[kpt][3];
            float a = aw[kpt];
            #pragma unroll
            for (int j = 0; j < 8; ++j) {
                float vs = w0 * bf2f((ushort_t)v0[j]);
                vs = fmaf(w1, bf2f((ushort_t)v1[j]), vs);
                vs = fmaf(w2, bf2f((ushort_t)v2[j]), vs);
                vs = fmaf(w3, bf2f((ushort_t)v3[j]), vs);
                acc[j] = fmaf(a, vs, acc[j]);
            }
        }
        short8 o8;
        #pragma unroll
        for (int j = 0; j < 8; ++j) o8[j] = (short)f2bf(acc[j]);
        *(short8*)(orow + co) = o8;
    }
}

// ------- depthwise 3x3 (both halves) + exact-GELU gate; 8 ch / thread ------
// t_pm [N][1024]: t1 = cols 0..511 (510,511 zero), t2 = cols 512..1023
// wT   [9][1024] bf16: w1 = cols 0..511, w2 = cols 512..1023 (padded zero)
// g_pm [N][512]  (cols 510,511 become 0 via zero weights)
__global__ __launch_bounds__(256) void dwgate_kernel(
    const ushort_t* __restrict__ t_pm,
    const ushort_t* __restrict__ wT,
    ushort_t* __restrict__ g_pm)
{
    int idx = blockIdx.x * 256 + threadIdx.x;  // over N*64
    int c0 = (idx & 63) * 8;
    int n  = idx >> 6;
    int y = n >> 7, x = n & 127;
    float a1[8] = {}, a2[8] = {};
    #pragma unroll
    for (int dy = 0; dy < 3; ++dy) {
        int yy = y + dy - 1;
        if (yy < 0 || yy > 127) continue;
        #pragma unroll
        for (int dx = 0; dx < 3; ++dx) {
            int xx = x + dx - 1;
            if (xx < 0 || xx > 127) continue;
            int p = dy * 3 + dx;
            const ushort_t* tr = t_pm + (size_t)(yy * WW + xx) * 1024;
            short8 t1 = *(const short8*)(tr + c0);
            short8 t2 = *(const short8*)(tr + 512 + c0);
            short8 w1 = *(const short8*)(wT + p * 1024 + c0);
            short8 w2 = *(const short8*)(wT + p * 1024 + 512 + c0);
            #pragma unroll
            for (int j = 0; j < 8; ++j) {
                a1[j] = fmaf(bf2f((ushort_t)t1[j]), bf2f((ushort_t)w1[j]), a1[j]);
                a2[j] = fmaf(bf2f((ushort_t)t2[j]), bf2f((ushort_t)w2[j]), a2[j]);
            }
        }
    }
    short8 o8;
    #pragma unroll
    for (int j = 0; j < 8; ++j) {
        float ge = 0.5f * a1[j] * (1.f + erff(a1[j] * 0.70710678118654752f));
        o8[j] = (short)f2bf(ge * a2[j]);
    }
    *(short8*)(g_pm + (size_t)n * 512 + c0) = o8;
}

extern "C" void kernel_launch(void* const* d_in, const int* in_sizes, int n_in,
                              void* d_out, int out_size, void* d_ws, size_t ws_size,
                              hipStream_t stream)
{
    const float* x      = (const float*)d_in[0];
    const float* ln1_w  = (const float*)d_in[1];
    const float* ln2_w  = (const float*)d_in[2];
    const float* qkv_w  = (const float*)d_in[3];
    const float* off_w  = (const float*)d_in[4];
    const float* rpb    = (const float*)d_in[5];
    const float* proj_w = (const float*)d_in[6];
    const float* pi_w   = (const float*)d_in[7];
    const float* dw_w   = (const float*)d_in[8];
    const float* po_w   = (const float*)d_in[9];
    float* out = (float*)d_out;

    // ---- workspace layout (ushort units) ----
    ushort_t* ws = (ushort_t*)d_ws;
    ushort_t* qkv_wb  = ws;                                  // 576*192
    ushort_t* off_wb  = qkv_wb  + 576 * 192;                 // 72*192
    ushort_t* proj_wb = off_wb  + 72 * 192;                  // 192*192
    ushort_t* pi_wb   = proj_wb + 192 * 192;                 // 1024*192 (remapped rows)
    ushort_t* po_wb   = pi_wb   + 1024 * 192;                // 192*512
    ushort_t* dwT     = po_wb   + 192 * 512;                 // 9*1024
    ushort_t* xn      = dwT     + 9 * 1024;                  // [N][192]  (also attn-out, xn2)
    ushort_t* qkvb    = xn      + (size_t)NN * CDIM;         // [12][N][48] (also g_pm [N][512])
    ushort_t* offb    = qkvb    + (size_t)12 * NN * 48;      // [4][N][24]
    ushort_t* t       = offb    + (size_t)4 * NN * 24;       // [N][1024]
    ushort_t* attn    = xn;
    ushort_t* g       = qkvb;

    dim3 blk(256);

    // weight conversions (once per call)
    convw_kernel<<<dim3((576 * 192 + 255) / 256), blk, 0, stream>>>(qkv_w,  qkv_wb,  576, 192, 192);
    convw_kernel<<<dim3((72 * 192 + 255) / 256),  blk, 0, stream>>>(off_w,  off_wb,  72,  192, 192);
    convw_kernel<<<dim3((192 * 192 + 255) / 256), blk, 0, stream>>>(proj_w, proj_wb, 192, 192, 192);
    convw_pi_kernel<<<dim3((1024 * 192 + 255) / 256), blk, 0, stream>>>(pi_w, pi_wb);
    convw_kernel<<<dim3((192 * 512 + 255) / 256), blk, 0, stream>>>(po_w,   po_wb,   192, 510, 512);
    convw_dw_kernel<<<dim3((9 * 1024 + 255) / 256), blk, 0, stream>>>(dw_w, dwT);

    const int shm192 = 64 * (192 + 8) * 2;   // 25600 B
    const int shm512 = 64 * (512 + 8) * 2;   // 66560 B

    for (int b = 0; b < BB; ++b) {
        const float* xb   = x   + (size_t)b * CDIM * NN;
        float*       outb = out + (size_t)b * CDIM * NN;

        // 1. xn1 = LN1(x)        (pixel-major bf16)
        ln_kernel<<<dim3(NN / 256), blk, 0, stream>>>(xb, ln1_w, xn);
        // 2. qkv planes = qkv_wb @ xn1
        gemm_mfma<0><<<dim3(NN / 64, 3), blk, shm192, stream>>>(
            qkv_wb, xn, nullptr, qkvb, 576, 192, 200);
        // 3. offsets = off_wb @ xn1
        gemm_mfma<1><<<dim3(NN / 64, 1), blk, shm192, stream>>>(
            off_wb, xn, nullptr, offb, 72, 192, 200);
        // 4. deformable attention (out aliases xn)
        attn_kernel<<<dim3(2 * 4 * NN / 256), blk, 0, stream>>>(qkvb, offb, rpb, attn);
        // 5. x1 = x + proj_wb @ attn  -> d_out (f32 channel-major)
        gemm_mfma<2><<<dim3(NN / 64, 1), blk, shm192, stream>>>(
            proj_wb, attn, xb, outb, 192, 192, 200);
        // 6. xn2 = LN2(x1)
        ln_kernel<<<dim3(NN / 256), blk, 0, stream>>>(outb, ln2_w, xn);
        // 7. t = pi_wb @ xn2   ([N][1024], rows pre-remapped, O=1024)
        gemm_mfma<3><<<dim3(NN / 64, 4), blk, shm192, stream>>>(
            pi_wb, xn, nullptr, t, 1024, 192, 200);
        // 8. g = gelu(dw(t1)) * dw(t2)   ([N][512], aliases qkvb)
        dwgate_kernel<<<dim3(NN * 64 / 256), blk, 0, stream>>>(t, dwT, g);
        // 9. out = x1 + po_wb @ g   (in-place residual on d_out)
        gemm_mfma<2><<<dim3(NN / 64, 1), blk, shm512, stream>>>(
            po_wb, g, outb, outb, 192, 512, 520);
    }
}

// Round 6
// 393.607 us; speedup vs baseline: 2.9914x; 1.0658x over previous
//
#include <hip/hip_runtime.h>
#include <math.h>

#define NN 16384      // H*W per image
#define WW 128
#define CDIM 192
#define HIDD 510
#define BB 2

typedef unsigned short ushort_t;
using short8 = __attribute__((ext_vector_type(8))) short;
using f32x4  = __attribute__((ext_vector_type(4))) float;

__device__ __forceinline__ float bf2f(ushort_t u) {
    union { unsigned int i; float f; } v; v.i = ((unsigned int)u) << 16; return v.f;
}
__device__ __forceinline__ ushort_t f2bf(float f) {
    union { unsigned int i; float f; } v; v.f = f;
    unsigned int i = v.i;
    return (ushort_t)((i + 0x7fffu + ((i >> 16) & 1u)) >> 16);  // RNE
}

// ---------------- weight f32 -> bf16 (with K padding) ----------------
__global__ __launch_bounds__(256) void convw_kernel(const float* __restrict__ src,
                                                    ushort_t* __restrict__ dst,
                                                    int O, int Kin, int Kout) {
    int idx = blockIdx.x * 256 + threadIdx.x;
    if (idx >= O * Kout) return;
    int o = idx / Kout, k = idx - o * Kout;
    dst[idx] = (k < Kin) ? f2bf(src[(size_t)o * Kin + k]) : (ushort_t)0;
}

// ---- pi weight rows remapped: rows 510,511,1022,1023 zero; o>=512 -> o-2 ----
__global__ __launch_bounds__(256) void convw_pi_kernel(const float* __restrict__ src,
                                                       ushort_t* __restrict__ dst) {
    int idx = blockIdx.x * 256 + threadIdx.x;   // 1024*192
    if (idx >= 1024 * 192) return;
    int o = idx / 192, k = idx - o * 192;
    bool zero = (o == 510) || (o == 511) || (o >= 1022);
    int so = (o < 510) ? o : o - 2;
    dst[idx] = zero ? (ushort_t)0 : f2bf(src[(size_t)so * 192 + k]);
}

// ---- dw weights [1020][9] f32 -> [9][2][512] bf16 (position-major) ----
__global__ __launch_bounds__(256) void convw_dw_kernel(const float* __restrict__ src,
                                                       ushort_t* __restrict__ dst) {
    int idx = blockIdx.x * 256 + threadIdx.x;   // 9*1024
    if (idx >= 9 * 1024) return;
    int p = idx >> 10, c = idx & 1023;
    int half = c >> 9, cc = c & 511;
    dst[idx] = (cc < HIDD) ? f2bf(src[(size_t)(half * HIDD + cc) * 9 + p]) : (ushort_t)0;
}

// ------------- BiasFree LayerNorm; out pixel-major [N][192] bf16 -----------
__global__ __launch_bounds__(256) void ln_kernel(const float* __restrict__ x,
                                                 const float* __restrict__ w,
                                                 ushort_t* __restrict__ y) {
    int b = blockIdx.y;
    int n = blockIdx.x * 256 + threadIdx.x;   // over N
    const float* xp = x + (size_t)b * CDIM * NN + n;
    float s = 0.f, s2 = 0.f;
    for (int c = 0; c < CDIM; ++c) {
        float v = xp[(size_t)c * NN];
        s += v; s2 += v * v;
    }
    const float inv = 1.f / (float)CDIM;
    float mu  = s * inv;
    float var = s2 * inv - mu * mu;
    float rs  = rsqrtf(var + 1e-5f);
    ushort_t* yp = y + (size_t)b * NN * CDIM + (size_t)n * CDIM;
    for (int c0 = 0; c0 < CDIM; c0 += 8) {
        short8 o8;
        #pragma unroll
        for (int j = 0; j < 8; ++j)
            o8[j] = (short)f2bf(xp[(size_t)(c0 + j) * NN] * rs * w[c0 + j]);
        *(short8*)(yp + c0) = o8;
    }
}

// ---------------- MFMA GEMM: acc[o,n] = sum_k Wb[o,k]*X_pm[n,k] ------------
// X pixel-major [N][K] bf16. Block: 64 n, (nw*64) o where nw=blockDim/64.
// blockIdx.z = batch. Strides xzs (ushort), yzs (elements), rzs (f32).
// MODE 0: bf16 out at ((o/48)*NN+n)*48 + o%48      (qkv planes)
// MODE 1: bf16 out at ((o/18)*NN+n)*24 + o%18      (offsets, scalar)
// MODE 2: f32  out at o*NN+n, += R                 (proj / po epilogues)
// MODE 3: bf16 out at n*1024 + o                   (pi -> t)
template<int MODE>
__global__ __launch_bounds__(256) void gemm_mfma(
    const ushort_t* __restrict__ Wb,
    const ushort_t* __restrict__ X,
    const float* __restrict__ R,
    void* __restrict__ Yv,
    int O, int K, int KP,
    size_t xzs, size_t yzs, size_t rzs)
{
    extern __shared__ ushort_t Xt[];   // [64][KP]
    int tid = threadIdx.x;
    int nw  = blockDim.x >> 6;
    int z   = blockIdx.z;
    int n0  = blockIdx.x * 64;
    const ushort_t* Xb = X + (size_t)z * xzs;

    // ---- stage X tile: direct vectorized row copy ----
    {
        int r = tid & 63;
        const ushort_t* src = Xb + (size_t)(n0 + r) * K;
        int nseg = K >> 3;
        for (int sseg = tid >> 6; sseg < nseg; sseg += nw)
            *(uint4*)&Xt[(size_t)r * KP + sseg * 8] = *(const uint4*)(src + sseg * 8);
    }
    __syncthreads();

    int w = tid >> 6, l = tid & 63;
    int o0w = blockIdx.y * (nw * 64) + w * 64;
    if (o0w >= O) return;

    int lrow = l & 15;
    int lk   = (l >> 4) * 8;

    f32x4 acc[4][4] = {};

    for (int kk0 = 0; kk0 < K; kk0 += 32) {
        short8 bfr[4];
        #pragma unroll
        for (int ni = 0; ni < 4; ++ni)
            bfr[ni] = *(const short8*)&Xt[(size_t)(ni * 16 + lrow) * KP + kk0 + lk];
        short8 afr[4];
        #pragma unroll
        for (int mi = 0; mi < 4; ++mi) {
            int orow = o0w + mi * 16 + lrow;
            if (orow < O)
                afr[mi] = *(const short8*)(Wb + (size_t)orow * K + kk0 + lk);
            else
                afr[mi] = short8{0,0,0,0,0,0,0,0};
        }
        #pragma unroll
        for (int mi = 0; mi < 4; ++mi)
            #pragma unroll
            for (int ni = 0; ni < 4; ++ni)
                acc[mi][ni] = __builtin_amdgcn_mfma_f32_16x16x32_bf16(
                    afr[mi], bfr[ni], acc[mi][ni], 0, 0, 0);
    }

    // ---- epilogue: D col(lane&15)=n, row=(lane>>4)*4+r = o ----
    int orow0 = (l >> 4) * 4;
    #pragma unroll
    for (int mi = 0; mi < 4; ++mi) {
        #pragma unroll
        for (int ni = 0; ni < 4; ++ni) {
            int n = n0 + ni * 16 + lrow;
            int obase = o0w + mi * 16 + orow0;
            float v0 = acc[mi][ni][0], v1 = acc[mi][ni][1];
            float v2 = acc[mi][ni][2], v3 = acc[mi][ni][3];
            if (MODE == 0 || MODE == 3) {
                if (obase >= O) continue;   // O multiple of 4; groups aligned
                unsigned int lo = (unsigned int)f2bf(v0) | ((unsigned int)f2bf(v1) << 16);
                unsigned int hi = (unsigned int)f2bf(v2) | ((unsigned int)f2bf(v3) << 16);
                size_t base = (MODE == 0)
                    ? ((size_t)(obase / 48) * NN + n) * 48 + (obase % 48)
                    : (size_t)n * 1024 + obase;
                *(uint2*)((ushort_t*)Yv + (size_t)z * yzs + base) = make_uint2(lo, hi);
            } else if (MODE == 1) {
                float vv[4] = {v0, v1, v2, v3};
                #pragma unroll
                for (int r = 0; r < 4; ++r) {
                    int o = obase + r;
                    if (o < O)
                        ((ushort_t*)Yv)[(size_t)z * yzs +
                            ((size_t)(o / 18) * NN + n) * 24 + (o % 18)] = f2bf(vv[r]);
                }
            } else {  // MODE 2
                float vv[4] = {v0, v1, v2, v3};
                #pragma unroll
                for (int r = 0; r < 4; ++r) {
                    int o = obase + r;
                    if (o < O) {
                        size_t idx = (size_t)o * NN + n;
                        ((float*)Yv)[(size_t)z * yzs + idx] = vv[r] + R[(size_t)z * rzs + idx];
                    }
                }
            }
        }
    }
}

// ------------- deformable attention, pixel-major, 2-lane split -------------
// qkv_pm: [B][12][N][48]  planes: q=h, k=4+h, v=8+h
// off_pm: [B][4][N][24]   (cols 0..17 valid: kpt*2 + {y,x})
// out_pm: [B][N][192]     col = h*48 + c
__global__ __launch_bounds__(256, 4) void attn_kernel(
    const ushort_t* __restrict__ qkv_pm,
    const ushort_t* __restrict__ off_pm,
    const float* __restrict__ rpb,     // [4,9]
    ushort_t* __restrict__ out_pm)
{
    int b = blockIdx.y;
    const ushort_t* qkvB = qkv_pm + (size_t)b * 12 * NN * 48;
    const ushort_t* offB = off_pm + (size_t)b * 4 * NN * 24;
    ushort_t*       outB = out_pm + (size_t)b * NN * CDIM;

    int idx = blockIdx.x * 256 + threadIdx.x;  // over 2*4*N
    int s   = idx & 1;
    int pix = idx >> 1;
    int n   = pix & (NN - 1);
    int h   = pix >> 14;
    int py = n >> 7, px = n & 127;

    // ---- offsets: contiguous 48B row ----
    union { uint4 u[3]; ushort_t v[24]; } ob;
    {
        const ushort_t* op = offB + ((size_t)h * NN + n) * 24;
        ob.u[0] = *(const uint4*)op;
        ob.u[1] = *(const uint4*)(op + 8);
        ob.u[2] = *(const uint4*)(op + 16);
    }

    // compressed per-kpt state: base offset (ushort units), dx/dy steps, fracs
    int   baseu[9], dxu[9], dyu[9];
    float wyA[9], wxA[9];
    #pragma unroll
    for (int kpt = 0; kpt < 9; ++kpt) {
        float oy = bf2f(ob.v[kpt * 2 + 0]);
        float ox = bf2f(ob.v[kpt * 2 + 1]);
        float cy = fminf(fmaxf((float)(py + (kpt / 3) - 1) + oy, 0.f), 127.f);
        float cx = fminf(fmaxf((float)(px + (kpt % 3) - 1) + ox, 0.f), 127.f);
        float y0f = floorf(cy), x0f = floorf(cx);
        wyA[kpt] = cy - y0f; wxA[kpt] = cx - x0f;
        int y0 = (int)y0f, x0 = (int)x0f;
        baseu[kpt] = (y0 * WW + x0) * 48;
        dxu[kpt]   = (x0 < 127) ? 48 : 0;
        dyu[kpt]   = (y0 < 127) ? (WW * 48) : 0;
    }

    const ushort_t* qrow  = qkvB + ((size_t)h * NN + n) * 48;
    const ushort_t* kbase = qkvB + ((size_t)(4 + h) * NN) * 48;
    const ushort_t* vbase = qkvB + ((size_t)(8 + h) * NN) * 48;
    int co0 = s * 24;

    // ---- unpack this lane's 24 q channels ----
    float qf[24];
    #pragma unroll
    for (int ch = 0; ch < 3; ++ch) {
        short8 q8 = *(const short8*)(qrow + co0 + ch * 8);
        #pragma unroll
        for (int j = 0; j < 8; ++j) qf[ch * 8 + j] = bf2f((ushort_t)q8[j]);
    }

    // ---- K phase: kpt-outer ----
    float logits[9];
    #pragma unroll
    for (int kpt = 0; kpt < 9; ++kpt) {
        float wy = wyA[kpt], wx = wxA[kpt];
        float iy = 1.f - wy, ix = 1.f - wx;
        float w0 = iy * ix, w1 = iy * wx, w2 = wy * ix, w3 = wy * wx;
        const ushort_t* kb = kbase + baseu[kpt] + co0;
        int du = dxu[kpt], dv = dyu[kpt];
        float acc = 0.f;
        #pragma unroll
        for (int ch = 0; ch < 3; ++ch) {
            const ushort_t* p = kb + ch * 8;
            short8 k0 = *(const short8*)p;
            short8 k1 = *(const short8*)(p + du);
            short8 k2 = *(const short8*)(p + dv);
            short8 k3 = *(const short8*)(p + dv + du);
            #pragma unroll
            for (int j = 0; j < 8; ++j) {
                float ks = w0 * bf2f((ushort_t)k0[j]);
                ks = fmaf(w1, bf2f((ushort_t)k1[j]), ks);
                ks = fmaf(w2, bf2f((ushort_t)k2[j]), ks);
                ks = fmaf(w3, bf2f((ushort_t)k3[j]), ks);
                acc = fmaf(qf[ch * 8 + j], ks, acc);
            }
        }
        logits[kpt] = acc;
    }

    // ---- reduce across lane pair, softmax ----
    #pragma unroll
    for (int kpt = 0; kpt < 9; ++kpt) {
        float v = logits[kpt] + __shfl_xor(logits[kpt], 1);
        logits[kpt] = v * 0.14433756729740643f + rpb[h * 9 + kpt];
    }
    float m = logits[0];
    #pragma unroll
    for (int i = 1; i < 9; ++i) m = fmaxf(m, logits[i]);
    float ssum = 0.f;
    #pragma unroll
    for (int i = 0; i < 9; ++i) { logits[i] = __expf(logits[i] - m); ssum += logits[i]; }
    float inv = 1.f / ssum;

    // ---- V phase: kpt-outer, attention weight folded into bilinear ----
    float oacc[24] = {};
    #pragma unroll
    for (int kpt = 0; kpt < 9; ++kpt) {
        float wy = wyA[kpt], wx = wxA[kpt];
        float iy = 1.f - wy, ix = 1.f - wx;
        float a = logits[kpt] * inv;
        float w0 = a * iy * ix, w1 = a * iy * wx, w2 = a * wy * ix, w3 = a * wy * wx;
        const ushort_t* vb = vbase + baseu[kpt] + co0;
        int du = dxu[kpt], dv = dyu[kpt];
        #pragma unroll
        for (int ch = 0; ch < 3; ++ch) {
            const ushort_t* p = vb + ch * 8;
            short8 v0 = *(const short8*)p;
            short8 v1 = *(const short8*)(p + du);
            short8 v2 = *(const short8*)(p + dv);
            short8 v3 = *(const short8*)(p + dv + du);
            #pragma unroll
            for (int j = 0; j < 8; ++j) {
                float vs = w0 * bf2f((ushort_t)v0[j]);
                vs = fmaf(w1, bf2f((ushort_t)v1[j]), vs);
                vs = fmaf(w2, bf2f((ushort_t)v2[j]), vs);
                vs = fmaf(w3, bf2f((ushort_t)v3[j]), vs);
                oacc[ch * 8 + j] += vs;
            }
        }
    }

    ushort_t* orow = outB + (size_t)n * CDIM + h * 48 + co0;
    #pragma unroll
    for (int ch = 0; ch < 3; ++ch) {
        short8 o8;
        #pragma unroll
        for (int j = 0; j < 8; ++j) o8[j] = (short)f2bf(oacc[ch * 8 + j]);
        *(short8*)(orow + ch * 8) = o8;
    }
}

// ------- depthwise 3x3 (both halves) + exact-GELU gate; 8 ch / thread ------
// t_pm [B][N][1024]: t1 = cols 0..511, t2 = cols 512..1023
// wT   [9][1024] bf16.  g_pm [B][N][512]
__global__ __launch_bounds__(256) void dwgate_kernel(
    const ushort_t* __restrict__ t_pm,
    const ushort_t* __restrict__ wT,
    ushort_t* __restrict__ g_pm)
{
    int b = blockIdx.y;
    const ushort_t* tB = t_pm + (size_t)b * NN * 1024;
    ushort_t*       gB = g_pm + (size_t)b * NN * 512;
    int idx = blockIdx.x * 256 + threadIdx.x;  // over N*64
    int c0 = (idx & 63) * 8;
    int n  = idx >> 6;
    int y = n >> 7, x = n & 127;
    float a1[8] = {}, a2[8] = {};
    #pragma unroll
    for (int dy = 0; dy < 3; ++dy) {
        int yy = y + dy - 1;
        if (yy < 0 || yy > 127) continue;
        #pragma unroll
        for (int dx = 0; dx < 3; ++dx) {
            int xx = x + dx - 1;
            if (xx < 0 || xx > 127) continue;
            int p = dy * 3 + dx;
            const ushort_t* tr = tB + (size_t)(yy * WW + xx) * 1024;
            short8 t1 = *(const short8*)(tr + c0);
            short8 t2 = *(const short8*)(tr + 512 + c0);
            short8 w1 = *(const short8*)(wT + p * 1024 + c0);
            short8 w2 = *(const short8*)(wT + p * 1024 + 512 + c0);
            #pragma unroll
            for (int j = 0; j < 8; ++j) {
                a1[j] = fmaf(bf2f((ushort_t)t1[j]), bf2f((ushort_t)w1[j]), a1[j]);
                a2[j] = fmaf(bf2f((ushort_t)t2[j]), bf2f((ushort_t)w2[j]), a2[j]);
            }
        }
    }
    short8 o8;
    #pragma unroll
    for (int j = 0; j < 8; ++j) {
        float ge = 0.5f * a1[j] * (1.f + erff(a1[j] * 0.70710678118654752f));
        o8[j] = (short)f2bf(ge * a2[j]);
    }
    *(short8*)(gB + (size_t)n * 512 + c0) = o8;
}

extern "C" void kernel_launch(void* const* d_in, const int* in_sizes, int n_in,
                              void* d_out, int out_size, void* d_ws, size_t ws_size,
                              hipStream_t stream)
{
    const float* x      = (const float*)d_in[0];
    const float* ln1_w  = (const float*)d_in[1];
    const float* ln2_w  = (const float*)d_in[2];
    const float* qkv_w  = (const float*)d_in[3];
    const float* off_w  = (const float*)d_in[4];
    const float* rpb    = (const float*)d_in[5];
    const float* proj_w = (const float*)d_in[6];
    const float* pi_w   = (const float*)d_in[7];
    const float* dw_w   = (const float*)d_in[8];
    const float* po_w   = (const float*)d_in[9];
    float* out = (float*)d_out;

    // ---- workspace layout (ushort units), ~125 MB, both batches resident ----
    ushort_t* ws = (ushort_t*)d_ws;
    ushort_t* qkv_wb  = ws;                                   // 576*192
    ushort_t* off_wb  = qkv_wb  + 576 * 192;
    ushort_t* proj_wb = off_wb  + 72 * 192;
    ushort_t* pi_wb   = proj_wb + 192 * 192;                  // 1024*192 remapped
    ushort_t* po_wb   = pi_wb   + 1024 * 192;                 // 192*512
    ushort_t* dwT     = po_wb   + 192 * 512;                  // 9*1024
    ushort_t* xn      = dwT     + 9 * 1024;                   // [2][N][192]  (also attn-out, xn2)
    ushort_t* qkvb    = xn      + (size_t)2 * NN * CDIM;      // [2][12][N][48] (also g [2][N][512])
    ushort_t* offb    = qkvb    + (size_t)2 * 12 * NN * 48;   // [2][4][N][24]
    ushort_t* t       = offb    + (size_t)2 * 4 * NN * 24;    // [2][N][1024]
    ushort_t* attn    = xn;
    ushort_t* g       = qkvb;

    dim3 blk(256);

    // weight conversions (once per call)
    convw_kernel<<<dim3((576 * 192 + 255) / 256), blk, 0, stream>>>(qkv_w,  qkv_wb,  576, 192, 192);
    convw_kernel<<<dim3((72 * 192 + 255) / 256),  blk, 0, stream>>>(off_w,  off_wb,  72,  192, 192);
    convw_kernel<<<dim3((192 * 192 + 255) / 256), blk, 0, stream>>>(proj_w, proj_wb, 192, 192, 192);
    convw_pi_kernel<<<dim3((1024 * 192 + 255) / 256), blk, 0, stream>>>(pi_w, pi_wb);
    convw_kernel<<<dim3((192 * 512 + 255) / 256), blk, 0, stream>>>(po_w,   po_wb,   192, 510, 512);
    convw_dw_kernel<<<dim3((9 * 1024 + 255) / 256), blk, 0, stream>>>(dw_w, dwT);

    const int shm192 = 64 * (192 + 8) * 2;   // 25600 B
    const int shm512 = 64 * (512 + 8) * 2;   // 66560 B
    const size_t XN_S   = (size_t)NN * CDIM;        // xn batch stride (ushort)
    const size_t QKV_S  = (size_t)12 * NN * 48;
    const size_t OFF_S  = (size_t)4 * NN * 24;
    const size_t T_S    = (size_t)NN * 1024;
    const size_t G_S    = (size_t)NN * 512;
    const size_t CM_S   = (size_t)CDIM * NN;        // channel-major f32 stride

    // 1. xn1 = LN1(x)   (both batches)
    ln_kernel<<<dim3(NN / 256, 2), blk, 0, stream>>>(x, ln1_w, xn);
    // 2. qkv planes = qkv_wb @ xn1   (192-thread blocks, 576 = 3*192)
    gemm_mfma<0><<<dim3(NN / 64, 3, 2), dim3(192), shm192, stream>>>(
        qkv_wb, xn, nullptr, qkvb, 576, 192, 200, XN_S, QKV_S, 0);
    // 3. offsets = off_wb @ xn1
    gemm_mfma<1><<<dim3(NN / 64, 1, 2), dim3(192), shm192, stream>>>(
        off_wb, xn, nullptr, offb, 72, 192, 200, XN_S, OFF_S, 0);
    // 4. deformable attention (out aliases xn)
    attn_kernel<<<dim3(2 * 4 * NN / 256, 2), blk, 0, stream>>>(qkvb, offb, rpb, attn);
    // 5. x1 = x + proj_wb @ attn  -> d_out (f32 channel-major)
    gemm_mfma<2><<<dim3(NN / 64, 1, 2), dim3(192), shm192, stream>>>(
        proj_wb, attn, x, out, 192, 192, 200, XN_S, CM_S, CM_S);
    // 6. xn2 = LN2(x1)
    ln_kernel<<<dim3(NN / 256, 2), blk, 0, stream>>>(out, ln2_w, xn);
    // 7. t = pi_wb @ xn2   ([N][1024], rows pre-remapped, O=1024)
    gemm_mfma<3><<<dim3(NN / 64, 4, 2), blk, shm192, stream>>>(
        pi_wb, xn, nullptr, t, 1024, 192, 200, XN_S, T_S, 0);
    // 8. g = gelu(dw(t1)) * dw(t2)   ([N][512], aliases qkvb)
    dwgate_kernel<<<dim3(NN * 64 / 256, 2), blk, 0, stream>>>(t, dwT, g);
    // 9. out = x1 + po_wb @ g   (in-place residual on d_out)
    gemm_mfma<2><<<dim3(NN / 64, 1, 2), dim3(192), shm512, stream>>>(
        po_wb, g, out, out, 192, 512, 520, G_S, CM_S, CM_S);
}

// Round 7
// 360.245 us; speedup vs baseline: 3.2684x; 1.0926x over previous
//
#include <hip/hip_runtime.h>
#include <math.h>

#define NN 16384      // H*W per image
#define WW 128
#define CDIM 192
#define HIDD 510
#define BB 2

typedef unsigned short ushort_t;
using short8 = __attribute__((ext_vector_type(8))) short;
using f32x4  = __attribute__((ext_vector_type(4))) float;

__device__ __forceinline__ float bf2f(ushort_t u) {
    union { unsigned int i; float f; } v; v.i = ((unsigned int)u) << 16; return v.f;
}
__device__ __forceinline__ ushort_t f2bf(float f) {
    union { unsigned int i; float f; } v; v.f = f;
    unsigned int i = v.i;
    return (ushort_t)((i + 0x7fffu + ((i >> 16) & 1u)) >> 16);  // RNE
}

// ---------------- weight f32 -> bf16 (with K padding) ----------------
__global__ __launch_bounds__(256) void convw_kernel(const float* __restrict__ src,
                                                    ushort_t* __restrict__ dst,
                                                    int O, int Kin, int Kout) {
    int idx = blockIdx.x * 256 + threadIdx.x;
    if (idx >= O * Kout) return;
    int o = idx / Kout, k = idx - o * Kout;
    dst[idx] = (k < Kin) ? f2bf(src[(size_t)o * Kin + k]) : (ushort_t)0;
}

// ---- pi weight rows remapped: rows 510,511,1022,1023 zero; o>=512 -> o-2 ----
__global__ __launch_bounds__(256) void convw_pi_kernel(const float* __restrict__ src,
                                                       ushort_t* __restrict__ dst) {
    int idx = blockIdx.x * 256 + threadIdx.x;   // 1024*192
    if (idx >= 1024 * 192) return;
    int o = idx / 192, k = idx - o * 192;
    bool zero = (o == 510) || (o == 511) || (o >= 1022);
    int so = (o < 510) ? o : o - 2;
    dst[idx] = zero ? (ushort_t)0 : f2bf(src[(size_t)so * 192 + k]);
}

// ---- dw weights [1020][9] f32 -> [9][2][512] bf16 (position-major) ----
__global__ __launch_bounds__(256) void convw_dw_kernel(const float* __restrict__ src,
                                                       ushort_t* __restrict__ dst) {
    int idx = blockIdx.x * 256 + threadIdx.x;   // 9*1024
    if (idx >= 9 * 1024) return;
    int p = idx >> 10, c = idx & 1023;
    int half = c >> 9, cc = c & 511;
    dst[idx] = (cc < HIDD) ? f2bf(src[(size_t)(half * HIDD + cc) * 9 + p]) : (ushort_t)0;
}

// ------------- BiasFree LayerNorm; out pixel-major [N][192] bf16 -----------
__global__ __launch_bounds__(256) void ln_kernel(const float* __restrict__ x,
                                                 const float* __restrict__ w,
                                                 ushort_t* __restrict__ y) {
    int b = blockIdx.y;
    int n = blockIdx.x * 256 + threadIdx.x;   // over N
    const float* xp = x + (size_t)b * CDIM * NN + n;
    float s = 0.f, s2 = 0.f;
    for (int c = 0; c < CDIM; ++c) {
        float v = xp[(size_t)c * NN];
        s += v; s2 += v * v;
    }
    const float inv = 1.f / (float)CDIM;
    float mu  = s * inv;
    float var = s2 * inv - mu * mu;
    float rs  = rsqrtf(var + 1e-5f);
    ushort_t* yp = y + (size_t)b * NN * CDIM + (size_t)n * CDIM;
    for (int c0 = 0; c0 < CDIM; c0 += 8) {
        short8 o8;
        #pragma unroll
        for (int j = 0; j < 8; ++j)
            o8[j] = (short)f2bf(xp[(size_t)(c0 + j) * NN] * rs * w[c0 + j]);
        *(short8*)(yp + c0) = o8;
    }
}

// ---------------- MFMA GEMM: acc[o,n] = sum_k Wb[o,k]*X_pm[n,k] ------------
// X pixel-major [N][K] bf16. Block: 64 n, (nw*64) o where nw=blockDim/64.
// blockIdx.z = batch. Strides xzs (ushort), yzs (elements), rzs (f32).
// MODE 0: bf16 out at ((o/48)*NN+n)*48 + o%48      (qkv planes)
// MODE 1: bf16 out at ((o/18)*NN+n)*24 + o%18      (offsets, scalar)
// MODE 2: f32  out at o*NN+n, += R                 (proj / po epilogues)
// MODE 3: bf16 out at n*1024 + o                   (pi -> t)
template<int MODE>
__global__ __launch_bounds__(256) void gemm_mfma(
    const ushort_t* __restrict__ Wb,
    const ushort_t* __restrict__ X,
    const float* __restrict__ R,
    void* __restrict__ Yv,
    int O, int K, int KP,
    size_t xzs, size_t yzs, size_t rzs)
{
    extern __shared__ ushort_t Xt[];   // [64][KP]
    int tid = threadIdx.x;
    int nw  = blockDim.x >> 6;
    int z   = blockIdx.z;
    int n0  = blockIdx.x * 64;
    const ushort_t* Xb = X + (size_t)z * xzs;

    // ---- stage X tile: direct vectorized row copy ----
    {
        int r = tid & 63;
        const ushort_t* src = Xb + (size_t)(n0 + r) * K;
        int nseg = K >> 3;
        for (int sseg = tid >> 6; sseg < nseg; sseg += nw)
            *(uint4*)&Xt[(size_t)r * KP + sseg * 8] = *(const uint4*)(src + sseg * 8);
    }
    __syncthreads();

    int w = tid >> 6, l = tid & 63;
    int o0w = blockIdx.y * (nw * 64) + w * 64;
    if (o0w >= O) return;

    int lrow = l & 15;
    int lk   = (l >> 4) * 8;

    f32x4 acc[4][4] = {};

    for (int kk0 = 0; kk0 < K; kk0 += 32) {
        short8 bfr[4];
        #pragma unroll
        for (int ni = 0; ni < 4; ++ni)
            bfr[ni] = *(const short8*)&Xt[(size_t)(ni * 16 + lrow) * KP + kk0 + lk];
        short8 afr[4];
        #pragma unroll
        for (int mi = 0; mi < 4; ++mi) {
            int orow = o0w + mi * 16 + lrow;
            if (orow < O)
                afr[mi] = *(const short8*)(Wb + (size_t)orow * K + kk0 + lk);
            else
                afr[mi] = short8{0,0,0,0,0,0,0,0};
        }
        #pragma unroll
        for (int mi = 0; mi < 4; ++mi)
            #pragma unroll
            for (int ni = 0; ni < 4; ++ni)
                acc[mi][ni] = __builtin_amdgcn_mfma_f32_16x16x32_bf16(
                    afr[mi], bfr[ni], acc[mi][ni], 0, 0, 0);
    }

    // ---- epilogue: D col(lane&15)=n, row=(lane>>4)*4+r = o ----
    int orow0 = (l >> 4) * 4;
    #pragma unroll
    for (int mi = 0; mi < 4; ++mi) {
        #pragma unroll
        for (int ni = 0; ni < 4; ++ni) {
            int n = n0 + ni * 16 + lrow;
            int obase = o0w + mi * 16 + orow0;
            float v0 = acc[mi][ni][0], v1 = acc[mi][ni][1];
            float v2 = acc[mi][ni][2], v3 = acc[mi][ni][3];
            if (MODE == 0 || MODE == 3) {
                if (obase >= O) continue;   // O multiple of 4; groups aligned
                unsigned int lo = (unsigned int)f2bf(v0) | ((unsigned int)f2bf(v1) << 16);
                unsigned int hi = (unsigned int)f2bf(v2) | ((unsigned int)f2bf(v3) << 16);
                size_t base = (MODE == 0)
                    ? ((size_t)(obase / 48) * NN + n) * 48 + (obase % 48)
                    : (size_t)n * 1024 + obase;
                *(uint2*)((ushort_t*)Yv + (size_t)z * yzs + base) = make_uint2(lo, hi);
            } else if (MODE == 1) {
                float vv[4] = {v0, v1, v2, v3};
                #pragma unroll
                for (int r = 0; r < 4; ++r) {
                    int o = obase + r;
                    if (o < O)
                        ((ushort_t*)Yv)[(size_t)z * yzs +
                            ((size_t)(o / 18) * NN + n) * 24 + (o % 18)] = f2bf(vv[r]);
                }
            } else {  // MODE 2
                float vv[4] = {v0, v1, v2, v3};
                #pragma unroll
                for (int r = 0; r < 4; ++r) {
                    int o = obase + r;
                    if (o < O) {
                        size_t idx = (size_t)o * NN + n;
                        ((float*)Yv)[(size_t)z * yzs + idx] = vv[r] + R[(size_t)z * rzs + idx];
                    }
                }
            }
        }
    }
}

// ------------- deformable attention, pixel-major, XCD-partitioned ----------
// 1024 blocks; XCD swizzle lin=(bid%8)*128+bid/8 gives each XCD one
// contiguous chunk of 128 blocks = exactly one (batch,head) plane
// (K+V working set 3.1 MB < 4 MB per-XCD L2). One block = one image row,
// 128 px x 2 lanes.
// qkv_pm: [B][12][N][48]  planes: q=h, k=4+h, v=8+h
// off_pm: [B][4][N][24]   (cols 0..17 valid: kpt*2 + {y,x})
// out_pm: [B][N][192]     col = h*48 + c
__global__ __launch_bounds__(256, 4) void attn_kernel(
    const ushort_t* __restrict__ qkv_pm,
    const ushort_t* __restrict__ off_pm,
    const float* __restrict__ rpb,     // [4,9]
    ushort_t* __restrict__ out_pm)
{
    int bid = blockIdx.x;                       // 0..1023
    int lin = (bid & 7) * 128 + (bid >> 3);     // XCD-contiguous ordering
    int bh  = lin >> 7;                         // 0..7 = b*4 + h
    int py  = lin & 127;                        // image row
    int b = bh >> 2, h = bh & 3;

    int tid = threadIdx.x;
    int s   = tid & 1;
    int px  = tid >> 1;                         // 0..127
    int n   = py * WW + px;

    const ushort_t* qkvB = qkv_pm + (size_t)b * 12 * NN * 48;
    const ushort_t* offB = off_pm + (size_t)b * 4 * NN * 24;
    ushort_t*       outB = out_pm + (size_t)b * NN * CDIM;

    // ---- offsets: contiguous 48B row ----
    union { uint4 u[3]; ushort_t v[24]; } ob;
    {
        const ushort_t* op = offB + ((size_t)h * NN + n) * 24;
        ob.u[0] = *(const uint4*)op;
        ob.u[1] = *(const uint4*)(op + 8);
        ob.u[2] = *(const uint4*)(op + 16);
    }

    // compressed per-kpt state: base offset (ushort units), dx/dy steps, fracs
    int   baseu[9], dxu[9], dyu[9];
    float wyA[9], wxA[9];
    #pragma unroll
    for (int kpt = 0; kpt < 9; ++kpt) {
        float oy = bf2f(ob.v[kpt * 2 + 0]);
        float ox = bf2f(ob.v[kpt * 2 + 1]);
        float cy = fminf(fmaxf((float)(py + (kpt / 3) - 1) + oy, 0.f), 127.f);
        float cx = fminf(fmaxf((float)(px + (kpt % 3) - 1) + ox, 0.f), 127.f);
        float y0f = floorf(cy), x0f = floorf(cx);
        wyA[kpt] = cy - y0f; wxA[kpt] = cx - x0f;
        int y0 = (int)y0f, x0 = (int)x0f;
        baseu[kpt] = (y0 * WW + x0) * 48;
        dxu[kpt]   = (x0 < 127) ? 48 : 0;
        dyu[kpt]   = (y0 < 127) ? (WW * 48) : 0;
    }

    const ushort_t* qrow  = qkvB + ((size_t)h * NN + n) * 48;
    const ushort_t* kbase = qkvB + ((size_t)(4 + h) * NN) * 48;
    const ushort_t* vbase = qkvB + ((size_t)(8 + h) * NN) * 48;
    int co0 = s * 24;

    // ---- unpack this lane's 24 q channels ----
    float qf[24];
    #pragma unroll
    for (int ch = 0; ch < 3; ++ch) {
        short8 q8 = *(const short8*)(qrow + co0 + ch * 8);
        #pragma unroll
        for (int j = 0; j < 8; ++j) qf[ch * 8 + j] = bf2f((ushort_t)q8[j]);
    }

    // ---- K phase: kpt-outer ----
    float logits[9];
    #pragma unroll
    for (int kpt = 0; kpt < 9; ++kpt) {
        float wy = wyA[kpt], wx = wxA[kpt];
        float iy = 1.f - wy, ix = 1.f - wx;
        float w0 = iy * ix, w1 = iy * wx, w2 = wy * ix, w3 = wy * wx;
        const ushort_t* kb = kbase + baseu[kpt] + co0;
        int du = dxu[kpt], dv = dyu[kpt];
        float acc = 0.f;
        #pragma unroll
        for (int ch = 0; ch < 3; ++ch) {
            const ushort_t* p = kb + ch * 8;
            short8 k0 = *(const short8*)p;
            short8 k1 = *(const short8*)(p + du);
            short8 k2 = *(const short8*)(p + dv);
            short8 k3 = *(const short8*)(p + dv + du);
            #pragma unroll
            for (int j = 0; j < 8; ++j) {
                float ks = w0 * bf2f((ushort_t)k0[j]);
                ks = fmaf(w1, bf2f((ushort_t)k1[j]), ks);
                ks = fmaf(w2, bf2f((ushort_t)k2[j]), ks);
                ks = fmaf(w3, bf2f((ushort_t)k3[j]), ks);
                acc = fmaf(qf[ch * 8 + j], ks, acc);
            }
        }
        logits[kpt] = acc;
    }

    // ---- reduce across lane pair, softmax ----
    #pragma unroll
    for (int kpt = 0; kpt < 9; ++kpt) {
        float v = logits[kpt] + __shfl_xor(logits[kpt], 1);
        logits[kpt] = v * 0.14433756729740643f + rpb[h * 9 + kpt];
    }
    float m = logits[0];
    #pragma unroll
    for (int i = 1; i < 9; ++i) m = fmaxf(m, logits[i]);
    float ssum = 0.f;
    #pragma unroll
    for (int i = 0; i < 9; ++i) { logits[i] = __expf(logits[i] - m); ssum += logits[i]; }
    float inv = 1.f / ssum;

    // ---- V phase: kpt-outer, attention weight folded into bilinear ----
    float oacc[24] = {};
    #pragma unroll
    for (int kpt = 0; kpt < 9; ++kpt) {
        float wy = wyA[kpt], wx = wxA[kpt];
        float iy = 1.f - wy, ix = 1.f - wx;
        float a = logits[kpt] * inv;
        float w0 = a * iy * ix, w1 = a * iy * wx, w2 = a * wy * ix, w3 = a * wy * wx;
        const ushort_t* vb = vbase + baseu[kpt] + co0;
        int du = dxu[kpt], dv = dyu[kpt];
        #pragma unroll
        for (int ch = 0; ch < 3; ++ch) {
            const ushort_t* p = vb + ch * 8;
            short8 v0 = *(const short8*)p;
            short8 v1 = *(const short8*)(p + du);
            short8 v2 = *(const short8*)(p + dv);
            short8 v3 = *(const short8*)(p + dv + du);
            #pragma unroll
            for (int j = 0; j < 8; ++j) {
                float vs = w0 * bf2f((ushort_t)v0[j]);
                vs = fmaf(w1, bf2f((ushort_t)v1[j]), vs);
                vs = fmaf(w2, bf2f((ushort_t)v2[j]), vs);
                vs = fmaf(w3, bf2f((ushort_t)v3[j]), vs);
                oacc[ch * 8 + j] += vs;
            }
        }
    }

    ushort_t* orow = outB + (size_t)n * CDIM + h * 48 + co0;
    #pragma unroll
    for (int ch = 0; ch < 3; ++ch) {
        short8 o8;
        #pragma unroll
        for (int j = 0; j < 8; ++j) o8[j] = (short)f2bf(oacc[ch * 8 + j]);
        *(short8*)(orow + ch * 8) = o8;
    }
}

// ------- depthwise 3x3 (both halves) + exact-GELU gate; 8 ch / thread ------
// t_pm [B][N][1024]: t1 = cols 0..511, t2 = cols 512..1023
// wT   [9][1024] bf16.  g_pm [B][N][512]
__global__ __launch_bounds__(256) void dwgate_kernel(
    const ushort_t* __restrict__ t_pm,
    const ushort_t* __restrict__ wT,
    ushort_t* __restrict__ g_pm)
{
    int b = blockIdx.y;
    const ushort_t* tB = t_pm + (size_t)b * NN * 1024;
    ushort_t*       gB = g_pm + (size_t)b * NN * 512;
    int idx = blockIdx.x * 256 + threadIdx.x;  // over N*64
    int c0 = (idx & 63) * 8;
    int n  = idx >> 6;
    int y = n >> 7, x = n & 127;
    float a1[8] = {}, a2[8] = {};
    #pragma unroll
    for (int dy = 0; dy < 3; ++dy) {
        int yy = y + dy - 1;
        if (yy < 0 || yy > 127) continue;
        #pragma unroll
        for (int dx = 0; dx < 3; ++dx) {
            int xx = x + dx - 1;
            if (xx < 0 || xx > 127) continue;
            int p = dy * 3 + dx;
            const ushort_t* tr = tB + (size_t)(yy * WW + xx) * 1024;
            short8 t1 = *(const short8*)(tr + c0);
            short8 t2 = *(const short8*)(tr + 512 + c0);
            short8 w1 = *(const short8*)(wT + p * 1024 + c0);
            short8 w2 = *(const short8*)(wT + p * 1024 + 512 + c0);
            #pragma unroll
            for (int j = 0; j < 8; ++j) {
                a1[j] = fmaf(bf2f((ushort_t)t1[j]), bf2f((ushort_t)w1[j]), a1[j]);
                a2[j] = fmaf(bf2f((ushort_t)t2[j]), bf2f((ushort_t)w2[j]), a2[j]);
            }
        }
    }
    short8 o8;
    #pragma unroll
    for (int j = 0; j < 8; ++j) {
        float ge = 0.5f * a1[j] * (1.f + erff(a1[j] * 0.70710678118654752f));
        o8[j] = (short)f2bf(ge * a2[j]);
    }
    *(short8*)(gB + (size_t)n * 512 + c0) = o8;
}

extern "C" void kernel_launch(void* const* d_in, const int* in_sizes, int n_in,
                              void* d_out, int out_size, void* d_ws, size_t ws_size,
                              hipStream_t stream)
{
    const float* x      = (const float*)d_in[0];
    const float* ln1_w  = (const float*)d_in[1];
    const float* ln2_w  = (const float*)d_in[2];
    const float* qkv_w  = (const float*)d_in[3];
    const float* off_w  = (const float*)d_in[4];
    const float* rpb    = (const float*)d_in[5];
    const float* proj_w = (const float*)d_in[6];
    const float* pi_w   = (const float*)d_in[7];
    const float* dw_w   = (const float*)d_in[8];
    const float* po_w   = (const float*)d_in[9];
    float* out = (float*)d_out;

    // ---- workspace layout (ushort units), ~125 MB, both batches resident ----
    ushort_t* ws = (ushort_t*)d_ws;
    ushort_t* qkv_wb  = ws;                                   // 576*192
    ushort_t* off_wb  = qkv_wb  + 576 * 192;
    ushort_t* proj_wb = off_wb  + 72 * 192;
    ushort_t* pi_wb   = proj_wb + 192 * 192;                  // 1024*192 remapped
    ushort_t* po_wb   = pi_wb   + 1024 * 192;                 // 192*512
    ushort_t* dwT     = po_wb   + 192 * 512;                  // 9*1024
    ushort_t* xn      = dwT     + 9 * 1024;                   // [2][N][192]  (also attn-out, xn2)
    ushort_t* qkvb    = xn      + (size_t)2 * NN * CDIM;      // [2][12][N][48] (also g [2][N][512])
    ushort_t* offb    = qkvb    + (size_t)2 * 12 * NN * 48;   // [2][4][N][24]
    ushort_t* t       = offb    + (size_t)2 * 4 * NN * 24;    // [2][N][1024]
    ushort_t* attn    = xn;
    ushort_t* g       = qkvb;

    dim3 blk(256);

    // weight conversions (once per call)
    convw_kernel<<<dim3((576 * 192 + 255) / 256), blk, 0, stream>>>(qkv_w,  qkv_wb,  576, 192, 192);
    convw_kernel<<<dim3((72 * 192 + 255) / 256),  blk, 0, stream>>>(off_w,  off_wb,  72,  192, 192);
    convw_kernel<<<dim3((192 * 192 + 255) / 256), blk, 0, stream>>>(proj_w, proj_wb, 192, 192, 192);
    convw_pi_kernel<<<dim3((1024 * 192 + 255) / 256), blk, 0, stream>>>(pi_w, pi_wb);
    convw_kernel<<<dim3((192 * 512 + 255) / 256), blk, 0, stream>>>(po_w,   po_wb,   192, 510, 512);
    convw_dw_kernel<<<dim3((9 * 1024 + 255) / 256), blk, 0, stream>>>(dw_w, dwT);

    const int shm192 = 64 * (192 + 8) * 2;   // 25600 B
    const int shm512 = 64 * (512 + 8) * 2;   // 66560 B
    const size_t XN_S   = (size_t)NN * CDIM;        // xn batch stride (ushort)
    const size_t QKV_S  = (size_t)12 * NN * 48;
    const size_t OFF_S  = (size_t)4 * NN * 24;
    const size_t T_S    = (size_t)NN * 1024;
    const size_t G_S    = (size_t)NN * 512;
    const size_t CM_S   = (size_t)CDIM * NN;        // channel-major f32 stride

    // 1. xn1 = LN1(x)   (both batches)
    ln_kernel<<<dim3(NN / 256, 2), blk, 0, stream>>>(x, ln1_w, xn);
    // 2. qkv planes = qkv_wb @ xn1   (192-thread blocks, 576 = 3*192)
    gemm_mfma<0><<<dim3(NN / 64, 3, 2), dim3(192), shm192, stream>>>(
        qkv_wb, xn, nullptr, qkvb, 576, 192, 200, XN_S, QKV_S, 0);
    // 3. offsets = off_wb @ xn1
    gemm_mfma<1><<<dim3(NN / 64, 1, 2), dim3(192), shm192, stream>>>(
        off_wb, xn, nullptr, offb, 72, 192, 200, XN_S, OFF_S, 0);
    // 4. deformable attention (out aliases xn); 1024 blocks, XCD-partitioned
    attn_kernel<<<dim3(1024), blk, 0, stream>>>(qkvb, offb, rpb, attn);
    // 5. x1 = x + proj_wb @ attn  -> d_out (f32 channel-major)
    gemm_mfma<2><<<dim3(NN / 64, 1, 2), dim3(192), shm192, stream>>>(
        proj_wb, attn, x, out, 192, 192, 200, XN_S, CM_S, CM_S);
    // 6. xn2 = LN2(x1)
    ln_kernel<<<dim3(NN / 256, 2), blk, 0, stream>>>(out, ln2_w, xn);
    // 7. t = pi_wb @ xn2   ([N][1024], rows pre-remapped, O=1024)
    gemm_mfma<3><<<dim3(NN / 64, 4, 2), blk, shm192, stream>>>(
        pi_wb, xn, nullptr, t, 1024, 192, 200, XN_S, T_S, 0);
    // 8. g = gelu(dw(t1)) * dw(t2)   ([N][512], aliases qkvb)
    dwgate_kernel<<<dim3(NN * 64 / 256, 2), blk, 0, stream>>>(t, dwT, g);
    // 9. out = x1 + po_wb @ g   (in-place residual on d_out)
    gemm_mfma<2><<<dim3(NN / 64, 1, 2), dim3(192), shm512, stream>>>(
        po_wb, g, out, out, 192, 512, 520, G_S, CM_S, CM_S);
}

// Round 8
// 359.935 us; speedup vs baseline: 3.2712x; 1.0009x over previous
//
#include <hip/hip_runtime.h>
#include <math.h>

#define NN 16384      // H*W per image
#define WW 128
#define CDIM 192
#define HIDD 510
#define BB 2

typedef unsigned short ushort_t;
using short8 = __attribute__((ext_vector_type(8))) short;
using f32x4  = __attribute__((ext_vector_type(4))) float;

__device__ __forceinline__ float bf2f(ushort_t u) {
    union { unsigned int i; float f; } v; v.i = ((unsigned int)u) << 16; return v.f;
}
__device__ __forceinline__ ushort_t f2bf(float f) {
    union { unsigned int i; float f; } v; v.f = f;
    unsigned int i = v.i;
    return (ushort_t)((i + 0x7fffu + ((i >> 16) & 1u)) >> 16);  // RNE
}

// ---------------- weight f32 -> bf16 (with K padding) ----------------
__global__ __launch_bounds__(256) void convw_kernel(const float* __restrict__ src,
                                                    ushort_t* __restrict__ dst,
                                                    int O, int Kin, int Kout) {
    int idx = blockIdx.x * 256 + threadIdx.x;
    if (idx >= O * Kout) return;
    int o = idx / Kout, k = idx - o * Kout;
    dst[idx] = (k < Kin) ? f2bf(src[(size_t)o * Kin + k]) : (ushort_t)0;
}

// ---- pi weight rows remapped: rows 510,511,1022,1023 zero; o>=512 -> o-2 ----
__global__ __launch_bounds__(256) void convw_pi_kernel(const float* __restrict__ src,
                                                       ushort_t* __restrict__ dst) {
    int idx = blockIdx.x * 256 + threadIdx.x;   // 1024*192
    if (idx >= 1024 * 192) return;
    int o = idx / 192, k = idx - o * 192;
    bool zero = (o == 510) || (o == 511) || (o >= 1022);
    int so = (o < 510) ? o : o - 2;
    dst[idx] = zero ? (ushort_t)0 : f2bf(src[(size_t)so * 192 + k]);
}

// ---- dw weights [1020][9] f32 -> [9][2][512] bf16 (position-major) ----
__global__ __launch_bounds__(256) void convw_dw_kernel(const float* __restrict__ src,
                                                       ushort_t* __restrict__ dst) {
    int idx = blockIdx.x * 256 + threadIdx.x;   // 9*1024
    if (idx >= 9 * 1024) return;
    int p = idx >> 10, c = idx & 1023;
    int half = c >> 9, cc = c & 511;
    dst[idx] = (cc < HIDD) ? f2bf(src[(size_t)(half * HIDD + cc) * 9 + p]) : (ushort_t)0;
}

// ------------- BiasFree LayerNorm; out pixel-major [N][192] bf16 -----------
__global__ __launch_bounds__(256) void ln_kernel(const float* __restrict__ x,
                                                 const float* __restrict__ w,
                                                 ushort_t* __restrict__ y) {
    int b = blockIdx.y;
    int n = blockIdx.x * 256 + threadIdx.x;   // over N
    const float* xp = x + (size_t)b * CDIM * NN + n;
    float s = 0.f, s2 = 0.f;
    for (int c = 0; c < CDIM; ++c) {
        float v = xp[(size_t)c * NN];
        s += v; s2 += v * v;
    }
    const float inv = 1.f / (float)CDIM;
    float mu  = s * inv;
    float var = s2 * inv - mu * mu;
    float rs  = rsqrtf(var + 1e-5f);
    ushort_t* yp = y + (size_t)b * NN * CDIM + (size_t)n * CDIM;
    for (int c0 = 0; c0 < CDIM; c0 += 8) {
        short8 o8;
        #pragma unroll
        for (int j = 0; j < 8; ++j)
            o8[j] = (short)f2bf(xp[(size_t)(c0 + j) * NN] * rs * w[c0 + j]);
        *(short8*)(yp + c0) = o8;
    }
}

// ---------------- MFMA GEMM: acc[o,n] = sum_k Wb[o,k]*X_pm[n,k] ------------
// XMODE 0: X pixel-major [N][K] bf16.
// XMODE 1: X = 4 planes [4][N][48] (K must be 192) — row n is the concat
//          of the 4 plane chunks (attn plane-major output).
// Block: 64 n, (nw*64) o where nw=blockDim/64. blockIdx.z = batch.
// MODE 0: bf16 out at ((o/48)*NN+n)*48 + o%48      (qkv planes)
// MODE 1: bf16 out at ((o/18)*NN+n)*24 + o%18      (offsets, scalar)
// MODE 2: f32  out at o*NN+n, += R                 (proj / po epilogues)
// MODE 3: bf16 out at n*1024 + o                   (pi -> t)
template<int MODE, int XMODE>
__global__ __launch_bounds__(256) void gemm_mfma(
    const ushort_t* __restrict__ Wb,
    const ushort_t* __restrict__ X,
    const float* __restrict__ R,
    void* __restrict__ Yv,
    int O, int K, int KP,
    size_t xzs, size_t yzs, size_t rzs)
{
    extern __shared__ ushort_t Xt[];   // [64][KP]
    int tid = threadIdx.x;
    int nw  = blockDim.x >> 6;
    int z   = blockIdx.z;
    int n0  = blockIdx.x * 64;
    const ushort_t* Xb = X + (size_t)z * xzs;

    // ---- stage X tile ----
    if (XMODE == 0) {
        int r = tid & 63;
        const ushort_t* src = Xb + (size_t)(n0 + r) * K;
        int nseg = K >> 3;
        for (int sseg = tid >> 6; sseg < nseg; sseg += nw)
            *(uint4*)&Xt[(size_t)r * KP + sseg * 8] = *(const uint4*)(src + sseg * 8);
    } else {
        int r = tid & 63;
        for (int seg = tid >> 6; seg < 24; seg += nw) {
            int plane = seg / 6, w8 = seg % 6;
            const ushort_t* src = Xb + ((size_t)plane * NN + n0 + r) * 48 + w8 * 8;
            *(uint4*)&Xt[(size_t)r * KP + seg * 8] = *(const uint4*)src;
        }
    }
    __syncthreads();

    int w = tid >> 6, l = tid & 63;
    int o0w = blockIdx.y * (nw * 64) + w * 64;
    if (o0w >= O) return;

    int lrow = l & 15;
    int lk   = (l >> 4) * 8;

    f32x4 acc[4][4] = {};

    for (int kk0 = 0; kk0 < K; kk0 += 32) {
        short8 bfr[4];
        #pragma unroll
        for (int ni = 0; ni < 4; ++ni)
            bfr[ni] = *(const short8*)&Xt[(size_t)(ni * 16 + lrow) * KP + kk0 + lk];
        short8 afr[4];
        #pragma unroll
        for (int mi = 0; mi < 4; ++mi) {
            int orow = o0w + mi * 16 + lrow;
            if (orow < O)
                afr[mi] = *(const short8*)(Wb + (size_t)orow * K + kk0 + lk);
            else
                afr[mi] = short8{0,0,0,0,0,0,0,0};
        }
        #pragma unroll
        for (int mi = 0; mi < 4; ++mi)
            #pragma unroll
            for (int ni = 0; ni < 4; ++ni)
                acc[mi][ni] = __builtin_amdgcn_mfma_f32_16x16x32_bf16(
                    afr[mi], bfr[ni], acc[mi][ni], 0, 0, 0);
    }

    // ---- epilogue: D col(lane&15)=n, row=(lane>>4)*4+r = o ----
    int orow0 = (l >> 4) * 4;
    #pragma unroll
    for (int mi = 0; mi < 4; ++mi) {
        #pragma unroll
        for (int ni = 0; ni < 4; ++ni) {
            int n = n0 + ni * 16 + lrow;
            int obase = o0w + mi * 16 + orow0;
            float v0 = acc[mi][ni][0], v1 = acc[mi][ni][1];
            float v2 = acc[mi][ni][2], v3 = acc[mi][ni][3];
            if (MODE == 0 || MODE == 3) {
                if (obase >= O) continue;   // O multiple of 4; groups aligned
                unsigned int lo = (unsigned int)f2bf(v0) | ((unsigned int)f2bf(v1) << 16);
                unsigned int hi = (unsigned int)f2bf(v2) | ((unsigned int)f2bf(v3) << 16);
                size_t base = (MODE == 0)
                    ? ((size_t)(obase / 48) * NN + n) * 48 + (obase % 48)
                    : (size_t)n * 1024 + obase;
                *(uint2*)((ushort_t*)Yv + (size_t)z * yzs + base) = make_uint2(lo, hi);
            } else if (MODE == 1) {
                float vv[4] = {v0, v1, v2, v3};
                #pragma unroll
                for (int r = 0; r < 4; ++r) {
                    int o = obase + r;
                    if (o < O)
                        ((ushort_t*)Yv)[(size_t)z * yzs +
                            ((size_t)(o / 18) * NN + n) * 24 + (o % 18)] = f2bf(vv[r]);
                }
            } else {  // MODE 2
                float vv[4] = {v0, v1, v2, v3};
                #pragma unroll
                for (int r = 0; r < 4; ++r) {
                    int o = obase + r;
                    if (o < O) {
                        size_t idx = (size_t)o * NN + n;
                        ((float*)Yv)[(size_t)z * yzs + idx] = vv[r] + R[(size_t)z * rzs + idx];
                    }
                }
            }
        }
    }
}

// ------------- deformable attention, plane-major in AND out ----------------
// 2048 blocks x 128 threads; lin=(bid%8)*256+bid/8 -> XCD i owns lin in
// [i*256,(i+1)*256) = one (batch,head): K+V working set 3.1 MB < 4 MB L2.
// One block = half an image row (64 px x 2 lanes).
// qkv_pm: [B][12][N][48]  planes: q=h, k=4+h, v=8+h
// off_pm: [B][4][N][24]
// out_pl: [B][4][N][48]   (plane-major: no cross-XCD line sharing)
__global__ __launch_bounds__(128, 4) void attn_kernel(
    const ushort_t* __restrict__ qkv_pm,
    const ushort_t* __restrict__ off_pm,
    const float* __restrict__ rpb,     // [4,9]
    ushort_t* __restrict__ out_pl)
{
    int bid = blockIdx.x;                       // 0..2047
    int lin = (bid & 7) * 256 + (bid >> 3);     // XCD-contiguous ordering
    int bh  = lin >> 8;                         // 0..7 = b*4 + h
    int b = bh >> 2, h = bh & 3;
    int rem = lin & 255;
    int py  = rem >> 1;                         // image row
    int tid = threadIdx.x;
    int s   = tid & 1;
    int px  = (rem & 1) * 64 + (tid >> 1);      // 0..127
    int n   = py * WW + px;

    const ushort_t* qkvB = qkv_pm + (size_t)b * 12 * NN * 48;
    const ushort_t* offB = off_pm + (size_t)b * 4 * NN * 24;

    // ---- offsets: contiguous 48B row ----
    union { uint4 u[3]; ushort_t v[24]; } ob;
    {
        const ushort_t* op = offB + ((size_t)h * NN + n) * 24;
        ob.u[0] = *(const uint4*)op;
        ob.u[1] = *(const uint4*)(op + 8);
        ob.u[2] = *(const uint4*)(op + 16);
    }

    // compressed per-kpt state: base offset (ushort units), dx/dy steps, fracs
    int   baseu[9], dxu[9], dyu[9];
    float wyA[9], wxA[9];
    #pragma unroll
    for (int kpt = 0; kpt < 9; ++kpt) {
        float oy = bf2f(ob.v[kpt * 2 + 0]);
        float ox = bf2f(ob.v[kpt * 2 + 1]);
        float cy = fminf(fmaxf((float)(py + (kpt / 3) - 1) + oy, 0.f), 127.f);
        float cx = fminf(fmaxf((float)(px + (kpt % 3) - 1) + ox, 0.f), 127.f);
        float y0f = floorf(cy), x0f = floorf(cx);
        wyA[kpt] = cy - y0f; wxA[kpt] = cx - x0f;
        int y0 = (int)y0f, x0 = (int)x0f;
        baseu[kpt] = (y0 * WW + x0) * 48;
        dxu[kpt]   = (x0 < 127) ? 48 : 0;
        dyu[kpt]   = (y0 < 127) ? (WW * 48) : 0;
    }

    const ushort_t* qrow  = qkvB + ((size_t)h * NN + n) * 48;
    const ushort_t* kbase = qkvB + ((size_t)(4 + h) * NN) * 48;
    const ushort_t* vbase = qkvB + ((size_t)(8 + h) * NN) * 48;
    int co0 = s * 24;

    // ---- unpack this lane's 24 q channels ----
    float qf[24];
    #pragma unroll
    for (int ch = 0; ch < 3; ++ch) {
        short8 q8 = *(const short8*)(qrow + co0 + ch * 8);
        #pragma unroll
        for (int j = 0; j < 8; ++j) qf[ch * 8 + j] = bf2f((ushort_t)q8[j]);
    }

    // ---- K phase: kpt-outer ----
    float logits[9];
    #pragma unroll
    for (int kpt = 0; kpt < 9; ++kpt) {
        float wy = wyA[kpt], wx = wxA[kpt];
        float iy = 1.f - wy, ix = 1.f - wx;
        float w0 = iy * ix, w1 = iy * wx, w2 = wy * ix, w3 = wy * wx;
        const ushort_t* kb = kbase + baseu[kpt] + co0;
        int du = dxu[kpt], dv = dyu[kpt];
        float acc = 0.f;
        #pragma unroll
        for (int ch = 0; ch < 3; ++ch) {
            const ushort_t* p = kb + ch * 8;
            short8 k0 = *(const short8*)p;
            short8 k1 = *(const short8*)(p + du);
            short8 k2 = *(const short8*)(p + dv);
            short8 k3 = *(const short8*)(p + dv + du);
            #pragma unroll
            for (int j = 0; j < 8; ++j) {
                float ks = w0 * bf2f((ushort_t)k0[j]);
                ks = fmaf(w1, bf2f((ushort_t)k1[j]), ks);
                ks = fmaf(w2, bf2f((ushort_t)k2[j]), ks);
                ks = fmaf(w3, bf2f((ushort_t)k3[j]), ks);
                acc = fmaf(qf[ch * 8 + j], ks, acc);
            }
        }
        logits[kpt] = acc;
    }

    // ---- reduce across lane pair, softmax ----
    #pragma unroll
    for (int kpt = 0; kpt < 9; ++kpt) {
        float v = logits[kpt] + __shfl_xor(logits[kpt], 1);
        logits[kpt] = v * 0.14433756729740643f + rpb[h * 9 + kpt];
    }
    float m = logits[0];
    #pragma unroll
    for (int i = 1; i < 9; ++i) m = fmaxf(m, logits[i]);
    float ssum = 0.f;
    #pragma unroll
    for (int i = 0; i < 9; ++i) { logits[i] = __expf(logits[i] - m); ssum += logits[i]; }
    float inv = 1.f / ssum;

    // ---- V phase: kpt-outer, attention weight folded into bilinear ----
    float oacc[24] = {};
    #pragma unroll
    for (int kpt = 0; kpt < 9; ++kpt) {
        float wy = wyA[kpt], wx = wxA[kpt];
        float iy = 1.f - wy, ix = 1.f - wx;
        float a = logits[kpt] * inv;
        float w0 = a * iy * ix, w1 = a * iy * wx, w2 = a * wy * ix, w3 = a * wy * wx;
        const ushort_t* vb = vbase + baseu[kpt] + co0;
        int du = dxu[kpt], dv = dyu[kpt];
        #pragma unroll
        for (int ch = 0; ch < 3; ++ch) {
            const ushort_t* p = vb + ch * 8;
            short8 v0 = *(const short8*)p;
            short8 v1 = *(const short8*)(p + du);
            short8 v2 = *(const short8*)(p + dv);
            short8 v3 = *(const short8*)(p + dv + du);
            #pragma unroll
            for (int j = 0; j < 8; ++j) {
                float vs = w0 * bf2f((ushort_t)v0[j]);
                vs = fmaf(w1, bf2f((ushort_t)v1[j]), vs);
                vs = fmaf(w2, bf2f((ushort_t)v2[j]), vs);
                vs = fmaf(w3, bf2f((ushort_t)v3[j]), vs);
                oacc[ch * 8 + j] += vs;
            }
        }
    }

    // ---- plane-major output: contiguous per block, private per XCD ----
    ushort_t* orow = out_pl + ((size_t)(b * 4 + h) * NN + n) * 48 + co0;
    #pragma unroll
    for (int ch = 0; ch < 3; ++ch) {
        short8 o8;
        #pragma unroll
        for (int j = 0; j < 8; ++j) o8[j] = (short)f2bf(oacc[ch * 8 + j]);
        *(short8*)(orow + ch * 8) = o8;
    }
}

// ------- depthwise 3x3 (both halves) + exact-GELU gate; 8 ch / thread ------
// t_pm [B][N][1024]: t1 = cols 0..511, t2 = cols 512..1023
// wT   [9][1024] bf16.  g_pm [B][N][512]
// XCD swizzle: contiguous 16-row n-chunks per XCD for halo L2 locality.
__global__ __launch_bounds__(256) void dwgate_kernel(
    const ushort_t* __restrict__ t_pm,
    const ushort_t* __restrict__ wT,
    ushort_t* __restrict__ g_pm)
{
    int b = blockIdx.y;
    const ushort_t* tB = t_pm + (size_t)b * NN * 1024;
    ushort_t*       gB = g_pm + (size_t)b * NN * 512;
    int bid = blockIdx.x;                        // 4096
    int lin = (bid & 7) * 512 + (bid >> 3);      // XCD-contiguous
    int idx = lin * 256 + threadIdx.x;           // over N*64
    int c0 = (idx & 63) * 8;
    int n  = idx >> 6;
    int y = n >> 7, x = n & 127;
    float a1[8] = {}, a2[8] = {};
    #pragma unroll
    for (int dy = 0; dy < 3; ++dy) {
        int yy = y + dy - 1;
        if (yy < 0 || yy > 127) continue;
        #pragma unroll
        for (int dx = 0; dx < 3; ++dx) {
            int xx = x + dx - 1;
            if (xx < 0 || xx > 127) continue;
            int p = dy * 3 + dx;
            const ushort_t* tr = tB + (size_t)(yy * WW + xx) * 1024;
            short8 t1 = *(const short8*)(tr + c0);
            short8 t2 = *(const short8*)(tr + 512 + c0);
            short8 w1 = *(const short8*)(wT + p * 1024 + c0);
            short8 w2 = *(const short8*)(wT + p * 1024 + 512 + c0);
            #pragma unroll
            for (int j = 0; j < 8; ++j) {
                a1[j] = fmaf(bf2f((ushort_t)t1[j]), bf2f((ushort_t)w1[j]), a1[j]);
                a2[j] = fmaf(bf2f((ushort_t)t2[j]), bf2f((ushort_t)w2[j]), a2[j]);
            }
        }
    }
    short8 o8;
    #pragma unroll
    for (int j = 0; j < 8; ++j) {
        float ge = 0.5f * a1[j] * (1.f + erff(a1[j] * 0.70710678118654752f));
        o8[j] = (short)f2bf(ge * a2[j]);
    }
    *(short8*)(gB + (size_t)n * 512 + c0) = o8;
}

extern "C" void kernel_launch(void* const* d_in, const int* in_sizes, int n_in,
                              void* d_out, int out_size, void* d_ws, size_t ws_size,
                              hipStream_t stream)
{
    const float* x      = (const float*)d_in[0];
    const float* ln1_w  = (const float*)d_in[1];
    const float* ln2_w  = (const float*)d_in[2];
    const float* qkv_w  = (const float*)d_in[3];
    const float* off_w  = (const float*)d_in[4];
    const float* rpb    = (const float*)d_in[5];
    const float* proj_w = (const float*)d_in[6];
    const float* pi_w   = (const float*)d_in[7];
    const float* dw_w   = (const float*)d_in[8];
    const float* po_w   = (const float*)d_in[9];
    float* out = (float*)d_out;

    // ---- workspace layout (ushort units), ~125 MB, both batches resident ----
    ushort_t* ws = (ushort_t*)d_ws;
    ushort_t* qkv_wb  = ws;                                   // 576*192
    ushort_t* off_wb  = qkv_wb  + 576 * 192;
    ushort_t* proj_wb = off_wb  + 72 * 192;
    ushort_t* pi_wb   = proj_wb + 192 * 192;                  // 1024*192 remapped
    ushort_t* po_wb   = pi_wb   + 1024 * 192;                 // 192*512
    ushort_t* dwT     = po_wb   + 192 * 512;                  // 9*1024
    ushort_t* xn      = dwT     + 9 * 1024;                   // [2][N][192]  (also attn-out [2][4][N][48], xn2)
    ushort_t* qkvb    = xn      + (size_t)2 * NN * CDIM;      // [2][12][N][48] (also g [2][N][512])
    ushort_t* offb    = qkvb    + (size_t)2 * 12 * NN * 48;   // [2][4][N][24]
    ushort_t* t       = offb    + (size_t)2 * 4 * NN * 24;    // [2][N][1024]
    ushort_t* attn    = xn;
    ushort_t* g       = qkvb;

    dim3 blk(256);

    // weight conversions (once per call)
    convw_kernel<<<dim3((576 * 192 + 255) / 256), blk, 0, stream>>>(qkv_w,  qkv_wb,  576, 192, 192);
    convw_kernel<<<dim3((72 * 192 + 255) / 256),  blk, 0, stream>>>(off_w,  off_wb,  72,  192, 192);
    convw_kernel<<<dim3((192 * 192 + 255) / 256), blk, 0, stream>>>(proj_w, proj_wb, 192, 192, 192);
    convw_pi_kernel<<<dim3((1024 * 192 + 255) / 256), blk, 0, stream>>>(pi_w, pi_wb);
    convw_kernel<<<dim3((192 * 512 + 255) / 256), blk, 0, stream>>>(po_w,   po_wb,   192, 510, 512);
    convw_dw_kernel<<<dim3((9 * 1024 + 255) / 256), blk, 0, stream>>>(dw_w, dwT);

    const int shm192 = 64 * (192 + 8) * 2;   // 25600 B
    const int shm512 = 64 * (512 + 8) * 2;   // 66560 B
    const size_t XN_S   = (size_t)NN * CDIM;        // xn batch stride (ushort)
    const size_t QKV_S  = (size_t)12 * NN * 48;
    const size_t OFF_S  = (size_t)4 * NN * 24;
    const size_t APL_S  = (size_t)4 * NN * 48;      // attn plane-major batch stride
    const size_t T_S    = (size_t)NN * 1024;
    const size_t G_S    = (size_t)NN * 512;
    const size_t CM_S   = (size_t)CDIM * NN;        // channel-major f32 stride

    // 1. xn1 = LN1(x)   (both batches)
    ln_kernel<<<dim3(NN / 256, 2), blk, 0, stream>>>(x, ln1_w, xn);
    // 2. qkv planes = qkv_wb @ xn1   (192-thread blocks, 576 = 3*192)
    gemm_mfma<0, 0><<<dim3(NN / 64, 3, 2), dim3(192), shm192, stream>>>(
        qkv_wb, xn, nullptr, qkvb, 576, 192, 200, XN_S, QKV_S, 0);
    // 3. offsets = off_wb @ xn1
    gemm_mfma<1, 0><<<dim3(NN / 64, 1, 2), dim3(192), shm192, stream>>>(
        off_wb, xn, nullptr, offb, 72, 192, 200, XN_S, OFF_S, 0);
    // 4. deformable attention -> plane-major (aliases xn)
    attn_kernel<<<dim3(2048), dim3(128), 0, stream>>>(qkvb, offb, rpb, attn);
    // 5. x1 = x + proj_wb @ attn  -> d_out (f32 channel-major; XMODE 1 staging)
    gemm_mfma<2, 1><<<dim3(NN / 64, 1, 2), dim3(192), shm192, stream>>>(
        proj_wb, attn, x, out, 192, 192, 200, APL_S, CM_S, CM_S);
    // 6. xn2 = LN2(x1)
    ln_kernel<<<dim3(NN / 256, 2), blk, 0, stream>>>(out, ln2_w, xn);
    // 7. t = pi_wb @ xn2   ([N][1024], rows pre-remapped, O=1024)
    gemm_mfma<3, 0><<<dim3(NN / 64, 4, 2), blk, shm192, stream>>>(
        pi_wb, xn, nullptr, t, 1024, 192, 200, XN_S, T_S, 0);
    // 8. g = gelu(dw(t1)) * dw(t2)   ([N][512], aliases qkvb)
    dwgate_kernel<<<dim3(NN * 64 / 256, 2), blk, 0, stream>>>(t, dwT, g);
    // 9. out = x1 + po_wb @ g   (in-place residual on d_out)
    gemm_mfma<2, 0><<<dim3(NN / 64, 1, 2), dim3(192), shm512, stream>>>(
        po_wb, g, out, out, 192, 512, 520, G_S, CM_S, CM_S);
}

// Round 9
// 285.470 us; speedup vs baseline: 4.1245x; 1.2608x over previous
//
#include <hip/hip_runtime.h>
#include <math.h>

#define NN 16384      // H*W per image
#define WW 128
#define CDIM 192
#define HIDD 510
#define BB 2

typedef unsigned short ushort_t;
using short8 = __attribute__((ext_vector_type(8))) short;
using s4v    = __attribute__((ext_vector_type(4))) short;
using f32x4  = __attribute__((ext_vector_type(4))) float;

__device__ __forceinline__ float bf2f(ushort_t u) {
    union { unsigned int i; float f; } v; v.i = ((unsigned int)u) << 16; return v.f;
}
__device__ __forceinline__ ushort_t f2bf(float f) {
    union { unsigned int i; float f; } v; v.f = f;
    unsigned int i = v.i;
    return (ushort_t)((i + 0x7fffu + ((i >> 16) & 1u)) >> 16);  // RNE
}

// ---------------- weight f32 -> bf16 (with K padding) ----------------
__global__ __launch_bounds__(256) void convw_kernel(const float* __restrict__ src,
                                                    ushort_t* __restrict__ dst,
                                                    int O, int Kin, int Kout) {
    int idx = blockIdx.x * 256 + threadIdx.x;
    if (idx >= O * Kout) return;
    int o = idx / Kout, k = idx - o * Kout;
    dst[idx] = (k < Kin) ? f2bf(src[(size_t)o * Kin + k]) : (ushort_t)0;
}

// ---- pi weight rows remapped: rows 510,511,1022,1023 zero; o>=512 -> o-2 ----
__global__ __launch_bounds__(256) void convw_pi_kernel(const float* __restrict__ src,
                                                       ushort_t* __restrict__ dst) {
    int idx = blockIdx.x * 256 + threadIdx.x;   // 1024*192
    if (idx >= 1024 * 192) return;
    int o = idx / 192, k = idx - o * 192;
    bool zero = (o == 510) || (o == 511) || (o >= 1022);
    int so = (o < 510) ? o : o - 2;
    dst[idx] = zero ? (ushort_t)0 : f2bf(src[(size_t)so * 192 + k]);
}

// ---- dw weights [1020][9] f32 -> [9][2][512] bf16 (position-major) ----
__global__ __launch_bounds__(256) void convw_dw_kernel(const float* __restrict__ src,
                                                       ushort_t* __restrict__ dst) {
    int idx = blockIdx.x * 256 + threadIdx.x;   // 9*1024
    if (idx >= 9 * 1024) return;
    int p = idx >> 10, c = idx & 1023;
    int half = c >> 9, cc = c & 511;
    dst[idx] = (cc < HIDD) ? f2bf(src[(size_t)(half * HIDD + cc) * 9 + p]) : (ushort_t)0;
}

// ------------- BiasFree LayerNorm; out pixel-major [N][192] bf16 -----------
__global__ __launch_bounds__(256) void ln_kernel(const float* __restrict__ x,
                                                 const float* __restrict__ w,
                                                 ushort_t* __restrict__ y) {
    int b = blockIdx.y;
    int n = blockIdx.x * 256 + threadIdx.x;   // over N
    const float* xp = x + (size_t)b * CDIM * NN + n;
    float s = 0.f, s2 = 0.f;
    for (int c = 0; c < CDIM; ++c) {
        float v = xp[(size_t)c * NN];
        s += v; s2 += v * v;
    }
    const float inv = 1.f / (float)CDIM;
    float mu  = s * inv;
    float var = s2 * inv - mu * mu;
    float rs  = rsqrtf(var + 1e-5f);
    ushort_t* yp = y + (size_t)b * NN * CDIM + (size_t)n * CDIM;
    for (int c0 = 0; c0 < CDIM; c0 += 8) {
        short8 o8;
        #pragma unroll
        for (int j = 0; j < 8; ++j)
            o8[j] = (short)f2bf(xp[(size_t)(c0 + j) * NN] * rs * w[c0 + j]);
        *(short8*)(yp + c0) = o8;
    }
}

// ---------------- MFMA GEMM: acc[o,n] = sum_k Wb[o,k]*X_pm[n,k] ------------
// XMODE 0: X pixel-major [N][K] bf16.
// XMODE 1: X = 4 planes [4][N][48] (K=192), attn plane-major output.
// MODE 0: bf16 out at ((o/48)*NN+n)*48 + o%48      (qkv planes)
// MODE 1: bf16 out at ((o/18)*NN+n)*24 + o%18      (offsets, scalar)
// MODE 2: f32  out at o*NN+n, += R                 (po epilogue)
// MODE 3: bf16 out at n*1024 + o                   (pi -> t)
// MODE 4: f32  out at o*NN+n, += R; ALSO fused LN -> bf16 XN2[n][192]
//         (requires O=192 covered by one block: grid.y==1, 192 threads)
template<int MODE, int XMODE>
__global__ __launch_bounds__(256) void gemm_mfma(
    const ushort_t* __restrict__ Wb,
    const ushort_t* __restrict__ X,
    const float* __restrict__ R,
    void* __restrict__ Yv,
    int O, int K, int KP,
    size_t xzs, size_t yzs, size_t rzs,
    const float* __restrict__ W2, ushort_t* __restrict__ XN2)
{
    extern __shared__ ushort_t Xt[];   // [64][KP]
    int tid = threadIdx.x;
    int nw  = blockDim.x >> 6;
    int z   = blockIdx.z;
    int n0  = blockIdx.x * 64;
    const ushort_t* Xb = X + (size_t)z * xzs;

    // ---- stage X tile ----
    if (XMODE == 0) {
        int r = tid & 63;
        const ushort_t* src = Xb + (size_t)(n0 + r) * K;
        int nseg = K >> 3;
        for (int sseg = tid >> 6; sseg < nseg; sseg += nw)
            *(uint4*)&Xt[(size_t)r * KP + sseg * 8] = *(const uint4*)(src + sseg * 8);
    } else {
        int r = tid & 63;
        for (int seg = tid >> 6; seg < 24; seg += nw) {
            int plane = seg / 6, w8 = seg % 6;
            const ushort_t* src = Xb + ((size_t)plane * NN + n0 + r) * 48 + w8 * 8;
            *(uint4*)&Xt[(size_t)r * KP + seg * 8] = *(const uint4*)src;
        }
    }
    __syncthreads();

    int w = tid >> 6, l = tid & 63;
    int o0w = blockIdx.y * (nw * 64) + w * 64;
    if (o0w >= O) return;

    int lrow = l & 15;
    int lk   = (l >> 4) * 8;

    f32x4 acc[4][4] = {};

    for (int kk0 = 0; kk0 < K; kk0 += 32) {
        short8 bfr[4];
        #pragma unroll
        for (int ni = 0; ni < 4; ++ni)
            bfr[ni] = *(const short8*)&Xt[(size_t)(ni * 16 + lrow) * KP + kk0 + lk];
        short8 afr[4];
        #pragma unroll
        for (int mi = 0; mi < 4; ++mi) {
            int orow = o0w + mi * 16 + lrow;
            if (orow < O)
                afr[mi] = *(const short8*)(Wb + (size_t)orow * K + kk0 + lk);
            else
                afr[mi] = short8{0,0,0,0,0,0,0,0};
        }
        #pragma unroll
        for (int mi = 0; mi < 4; ++mi)
            #pragma unroll
            for (int ni = 0; ni < 4; ++ni)
                acc[mi][ni] = __builtin_amdgcn_mfma_f32_16x16x32_bf16(
                    afr[mi], bfr[ni], acc[mi][ni], 0, 0, 0);
    }

    // ---- epilogue: D col(lane&15)=n, row=(lane>>4)*4+r = o ----
    int orow0 = (l >> 4) * 4;

    if constexpr (MODE == 4) {
        __shared__ float red[3][64][2];
        float s[4] = {}, s2[4] = {};
        #pragma unroll
        for (int mi = 0; mi < 4; ++mi)
            #pragma unroll
            for (int ni = 0; ni < 4; ++ni) {
                int n = n0 + ni * 16 + lrow;
                int obase = o0w + mi * 16 + orow0;
                #pragma unroll
                for (int r = 0; r < 4; ++r) {
                    float v = acc[mi][ni][r] +
                              R[(size_t)z * rzs + (size_t)(obase + r) * NN + n];
                    acc[mi][ni][r] = v;
                    s[ni] += v; s2[ni] += v * v;
                }
            }
        #pragma unroll
        for (int ni = 0; ni < 4; ++ni) {
            s[ni]  += __shfl_xor(s[ni], 16);  s[ni]  += __shfl_xor(s[ni], 32);
            s2[ni] += __shfl_xor(s2[ni], 16); s2[ni] += __shfl_xor(s2[ni], 32);
        }
        if (l < 16) {
            #pragma unroll
            for (int ni = 0; ni < 4; ++ni) {
                red[w][ni * 16 + l][0] = s[ni];
                red[w][ni * 16 + l][1] = s2[ni];
            }
        }
        __syncthreads();
        float rsv[4];
        #pragma unroll
        for (int ni = 0; ni < 4; ++ni) {
            int nl = ni * 16 + lrow;
            float ts  = red[0][nl][0] + red[1][nl][0] + red[2][nl][0];
            float ts2 = red[0][nl][1] + red[1][nl][1] + red[2][nl][1];
            float mu  = ts * (1.f / 192.f);
            float var = ts2 * (1.f / 192.f) - mu * mu;
            rsv[ni] = rsqrtf(var + 1e-5f);
        }
        #pragma unroll
        for (int mi = 0; mi < 4; ++mi)
            #pragma unroll
            for (int ni = 0; ni < 4; ++ni) {
                int n = n0 + ni * 16 + lrow;
                int obase = o0w + mi * 16 + orow0;
                #pragma unroll
                for (int r = 0; r < 4; ++r)
                    ((float*)Yv)[(size_t)z * yzs + (size_t)(obase + r) * NN + n]
                        = acc[mi][ni][r];
                float rs_ = rsv[ni];
                unsigned int lo =
                    (unsigned int)f2bf(acc[mi][ni][0] * rs_ * W2[obase])
                  | ((unsigned int)f2bf(acc[mi][ni][1] * rs_ * W2[obase + 1]) << 16);
                unsigned int hi =
                    (unsigned int)f2bf(acc[mi][ni][2] * rs_ * W2[obase + 2])
                  | ((unsigned int)f2bf(acc[mi][ni][3] * rs_ * W2[obase + 3]) << 16);
                *(uint2*)(XN2 + (size_t)z * ((size_t)NN * CDIM)
                          + (size_t)n * CDIM + obase) = make_uint2(lo, hi);
            }
    } else {
        #pragma unroll
        for (int mi = 0; mi < 4; ++mi) {
            #pragma unroll
            for (int ni = 0; ni < 4; ++ni) {
                int n = n0 + ni * 16 + lrow;
                int obase = o0w + mi * 16 + orow0;
                float v0 = acc[mi][ni][0], v1 = acc[mi][ni][1];
                float v2 = acc[mi][ni][2], v3 = acc[mi][ni][3];
                if (MODE == 0 || MODE == 3) {
                    if (obase >= O) continue;
                    unsigned int lo = (unsigned int)f2bf(v0) | ((unsigned int)f2bf(v1) << 16);
                    unsigned int hi = (unsigned int)f2bf(v2) | ((unsigned int)f2bf(v3) << 16);
                    size_t base = (MODE == 0)
                        ? ((size_t)(obase / 48) * NN + n) * 48 + (obase % 48)
                        : (size_t)n * 1024 + obase;
                    *(uint2*)((ushort_t*)Yv + (size_t)z * yzs + base) = make_uint2(lo, hi);
                } else if (MODE == 1) {
                    float vv[4] = {v0, v1, v2, v3};
                    #pragma unroll
                    for (int r = 0; r < 4; ++r) {
                        int o = obase + r;
                        if (o < O)
                            ((ushort_t*)Yv)[(size_t)z * yzs +
                                ((size_t)(o / 18) * NN + n) * 24 + (o % 18)] = f2bf(vv[r]);
                    }
                } else {  // MODE 2
                    float vv[4] = {v0, v1, v2, v3};
                    #pragma unroll
                    for (int r = 0; r < 4; ++r) {
                        int o = obase + r;
                        if (o < O) {
                            size_t idx = (size_t)o * NN + n;
                            ((float*)Yv)[(size_t)z * yzs + idx] = vv[r] + R[(size_t)z * rzs + idx];
                        }
                    }
                }
            }
        }
    }
}

// ------------- deformable attention, per-batch, 4-way channel split --------
// 1024 blocks x 256 thr; lin=(bid%8)*128+bid/8 -> XCD i owns chunk i =
// (head i/2, row-half i%2): K/V footprint ~1.6 MB < 4 MB per-XCD L2.
// Block = 64 px x 4 lanes (12 ch each).
// qkvB: [12][N][48] (one batch)  planes: q=h, k=4+h, v=8+h
// offB: [4][N][24]
// outB: [4][N][48] plane-major
__global__ __launch_bounds__(256, 4) void attn_kernel(
    const ushort_t* __restrict__ qkvB,
    const ushort_t* __restrict__ offB,
    const float* __restrict__ rpb,     // [4,9]
    ushort_t* __restrict__ outB)
{
    int bid = blockIdx.x;                       // 0..1023
    int lin = (bid & 7) * 128 + (bid >> 3);     // XCD-contiguous
    int c   = lin >> 7;                         // 0..7
    int h   = c >> 1;
    int half= c & 1;
    int r   = lin & 127;
    int py  = half * 64 + (r >> 1);
    int tid = threadIdx.x;
    int px  = (r & 1) * 64 + (tid >> 2);
    int s   = tid & 3;
    int n   = py * WW + px;

    // ---- offsets: contiguous 48B row ----
    union { uint4 u[3]; ushort_t v[24]; } ob;
    {
        const ushort_t* op = offB + ((size_t)h * NN + n) * 24;
        ob.u[0] = *(const uint4*)op;
        ob.u[1] = *(const uint4*)(op + 8);
        ob.u[2] = *(const uint4*)(op + 16);
    }

    int   baseu[9], dxu[9], dyu[9];
    float wyA[9], wxA[9];
    #pragma unroll
    for (int kpt = 0; kpt < 9; ++kpt) {
        float oy = bf2f(ob.v[kpt * 2 + 0]);
        float ox = bf2f(ob.v[kpt * 2 + 1]);
        float cy = fminf(fmaxf((float)(py + (kpt / 3) - 1) + oy, 0.f), 127.f);
        float cx = fminf(fmaxf((float)(px + (kpt % 3) - 1) + ox, 0.f), 127.f);
        float y0f = floorf(cy), x0f = floorf(cx);
        wyA[kpt] = cy - y0f; wxA[kpt] = cx - x0f;
        int y0 = (int)y0f, x0 = (int)x0f;
        baseu[kpt] = (y0 * WW + x0) * 48;
        dxu[kpt]   = (x0 < 127) ? 48 : 0;
        dyu[kpt]   = (y0 < 127) ? (WW * 48) : 0;
    }

    const ushort_t* qrow  = qkvB + ((size_t)h * NN + n) * 48;
    const ushort_t* kbase = qkvB + ((size_t)(4 + h) * NN) * 48;
    const ushort_t* vbase = qkvB + ((size_t)(8 + h) * NN) * 48;
    int co0 = s * 12;

    // ---- this lane's 12 q channels ----
    float qf[12];
    #pragma unroll
    for (int ch = 0; ch < 3; ++ch) {
        s4v q4 = *(const s4v*)(qrow + co0 + ch * 4);
        #pragma unroll
        for (int j = 0; j < 4; ++j) qf[ch * 4 + j] = bf2f((ushort_t)q4[j]);
    }

    // ---- K phase ----
    float logits[9];
    #pragma unroll
    for (int kpt = 0; kpt < 9; ++kpt) {
        float wy = wyA[kpt], wx = wxA[kpt];
        float iy = 1.f - wy, ix = 1.f - wx;
        float w0 = iy * ix, w1 = iy * wx, w2 = wy * ix, w3 = wy * wx;
        const ushort_t* kb = kbase + baseu[kpt] + co0;
        int du = dxu[kpt], dv = dyu[kpt];
        float acc = 0.f;
        #pragma unroll
        for (int ch = 0; ch < 3; ++ch) {
            const ushort_t* p = kb + ch * 4;
            s4v k0 = *(const s4v*)p;
            s4v k1 = *(const s4v*)(p + du);
            s4v k2 = *(const s4v*)(p + dv);
            s4v k3 = *(const s4v*)(p + dv + du);
            #pragma unroll
            for (int j = 0; j < 4; ++j) {
                float ks = w0 * bf2f((ushort_t)k0[j]);
                ks = fmaf(w1, bf2f((ushort_t)k1[j]), ks);
                ks = fmaf(w2, bf2f((ushort_t)k2[j]), ks);
                ks = fmaf(w3, bf2f((ushort_t)k3[j]), ks);
                acc = fmaf(qf[ch * 4 + j], ks, acc);
            }
        }
        logits[kpt] = acc;
    }

    // ---- reduce across 4-lane group, softmax ----
    #pragma unroll
    for (int kpt = 0; kpt < 9; ++kpt) {
        float v = logits[kpt];
        v += __shfl_xor(v, 1);
        v += __shfl_xor(v, 2);
        logits[kpt] = v * 0.14433756729740643f + rpb[h * 9 + kpt];
    }
    float m = logits[0];
    #pragma unroll
    for (int i = 1; i < 9; ++i) m = fmaxf(m, logits[i]);
    float ssum = 0.f;
    #pragma unroll
    for (int i = 0; i < 9; ++i) { logits[i] = __expf(logits[i] - m); ssum += logits[i]; }
    float inv = 1.f / ssum;

    // ---- V phase ----
    float oacc[12] = {};
    #pragma unroll
    for (int kpt = 0; kpt < 9; ++kpt) {
        float wy = wyA[kpt], wx = wxA[kpt];
        float iy = 1.f - wy, ix = 1.f - wx;
        float a = logits[kpt] * inv;
        float w0 = a * iy * ix, w1 = a * iy * wx, w2 = a * wy * ix, w3 = a * wy * wx;
        const ushort_t* vb = vbase + baseu[kpt] + co0;
        int du = dxu[kpt], dv = dyu[kpt];
        #pragma unroll
        for (int ch = 0; ch < 3; ++ch) {
            const ushort_t* p = vb + ch * 4;
            s4v v0 = *(const s4v*)p;
            s4v v1 = *(const s4v*)(p + du);
            s4v v2 = *(const s4v*)(p + dv);
            s4v v3 = *(const s4v*)(p + dv + du);
            #pragma unroll
            for (int j = 0; j < 4; ++j) {
                float vs = w0 * bf2f((ushort_t)v0[j]);
                vs = fmaf(w1, bf2f((ushort_t)v1[j]), vs);
                vs = fmaf(w2, bf2f((ushort_t)v2[j]), vs);
                vs = fmaf(w3, bf2f((ushort_t)v3[j]), vs);
                oacc[ch * 4 + j] += vs;
            }
        }
    }

    ushort_t* orow = outB + ((size_t)h * NN + n) * 48 + co0;
    #pragma unroll
    for (int ch = 0; ch < 3; ++ch) {
        s4v o4;
        #pragma unroll
        for (int j = 0; j < 4; ++j) o4[j] = (short)f2bf(oacc[ch * 4 + j]);
        *(s4v*)(orow + ch * 4) = o4;
    }
}

// ------- depthwise 3x3 (both halves) + exact-GELU gate; 8 ch / thread ------
__global__ __launch_bounds__(256) void dwgate_kernel(
    const ushort_t* __restrict__ t_pm,
    const ushort_t* __restrict__ wT,
    ushort_t* __restrict__ g_pm)
{
    int b = blockIdx.y;
    const ushort_t* tB = t_pm + (size_t)b * NN * 1024;
    ushort_t*       gB = g_pm + (size_t)b * NN * 512;
    int bid = blockIdx.x;                        // 4096
    int lin = (bid & 7) * 512 + (bid >> 3);      // XCD-contiguous
    int idx = lin * 256 + threadIdx.x;           // over N*64
    int c0 = (idx & 63) * 8;
    int n  = idx >> 6;
    int y = n >> 7, x = n & 127;
    float a1[8] = {}, a2[8] = {};
    #pragma unroll
    for (int dy = 0; dy < 3; ++dy) {
        int yy = y + dy - 1;
        if (yy < 0 || yy > 127) continue;
        #pragma unroll
        for (int dx = 0; dx < 3; ++dx) {
            int xx = x + dx - 1;
            if (xx < 0 || xx > 127) continue;
            int p = dy * 3 + dx;
            const ushort_t* tr = tB + (size_t)(yy * WW + xx) * 1024;
            short8 t1 = *(const short8*)(tr + c0);
            short8 t2 = *(const short8*)(tr + 512 + c0);
            short8 w1 = *(const short8*)(wT + p * 1024 + c0);
            short8 w2 = *(const short8*)(wT + p * 1024 + 512 + c0);
            #pragma unroll
            for (int j = 0; j < 8; ++j) {
                a1[j] = fmaf(bf2f((ushort_t)t1[j]), bf2f((ushort_t)w1[j]), a1[j]);
                a2[j] = fmaf(bf2f((ushort_t)t2[j]), bf2f((ushort_t)w2[j]), a2[j]);
            }
        }
    }
    short8 o8;
    #pragma unroll
    for (int j = 0; j < 8; ++j) {
        float ge = 0.5f * a1[j] * (1.f + erff(a1[j] * 0.70710678118654752f));
        o8[j] = (short)f2bf(ge * a2[j]);
    }
    *(short8*)(gB + (size_t)n * 512 + c0) = o8;
}

extern "C" void kernel_launch(void* const* d_in, const int* in_sizes, int n_in,
                              void* d_out, int out_size, void* d_ws, size_t ws_size,
                              hipStream_t stream)
{
    const float* x      = (const float*)d_in[0];
    const float* ln1_w  = (const float*)d_in[1];
    const float* ln2_w  = (const float*)d_in[2];
    const float* qkv_w  = (const float*)d_in[3];
    const float* off_w  = (const float*)d_in[4];
    const float* rpb    = (const float*)d_in[5];
    const float* proj_w = (const float*)d_in[6];
    const float* pi_w   = (const float*)d_in[7];
    const float* dw_w   = (const float*)d_in[8];
    const float* po_w   = (const float*)d_in[9];
    float* out = (float*)d_out;

    // ---- workspace layout (ushort units), ~137 MB ----
    ushort_t* ws = (ushort_t*)d_ws;
    ushort_t* qkv_wb  = ws;                                   // 576*192
    ushort_t* off_wb  = qkv_wb  + 576 * 192;
    ushort_t* proj_wb = off_wb  + 72 * 192;
    ushort_t* pi_wb   = proj_wb + 192 * 192;                  // 1024*192 remapped
    ushort_t* po_wb   = pi_wb   + 1024 * 192;                 // 192*512
    ushort_t* dwT     = po_wb   + 192 * 512;                  // 9*1024
    ushort_t* xn      = dwT     + 9 * 1024;                   // [2][N][192] (LN1 out; also attn-out [2][4][N][48])
    ushort_t* qkvb    = xn      + (size_t)2 * NN * CDIM;      // [2][12][N][48] (also g [2][N][512])
    ushort_t* offb    = qkvb    + (size_t)2 * 12 * NN * 48;   // [2][4][N][24]
    ushort_t* t       = offb    + (size_t)2 * 4 * NN * 24;    // [2][N][1024]
    ushort_t* xn2     = t       + (size_t)2 * NN * 1024;      // [2][N][192]
    ushort_t* attn    = xn;
    ushort_t* g       = qkvb;

    dim3 blk(256);

    // weight conversions (once per call)
    convw_kernel<<<dim3((576 * 192 + 255) / 256), blk, 0, stream>>>(qkv_w,  qkv_wb,  576, 192, 192);
    convw_kernel<<<dim3((72 * 192 + 255) / 256),  blk, 0, stream>>>(off_w,  off_wb,  72,  192, 192);
    convw_kernel<<<dim3((192 * 192 + 255) / 256), blk, 0, stream>>>(proj_w, proj_wb, 192, 192, 192);
    convw_pi_kernel<<<dim3((1024 * 192 + 255) / 256), blk, 0, stream>>>(pi_w, pi_wb);
    convw_kernel<<<dim3((192 * 512 + 255) / 256), blk, 0, stream>>>(po_w,   po_wb,   192, 510, 512);
    convw_dw_kernel<<<dim3((9 * 1024 + 255) / 256), blk, 0, stream>>>(dw_w, dwT);

    const int shm192 = 64 * (192 + 8) * 2;   // 25600 B
    const int shm512 = 64 * (512 + 8) * 2;   // 66560 B
    const size_t XN_S   = (size_t)NN * CDIM;
    const size_t QKV_S  = (size_t)12 * NN * 48;
    const size_t OFF_S  = (size_t)4 * NN * 24;
    const size_t APL_S  = (size_t)4 * NN * 48;
    const size_t T_S    = (size_t)NN * 1024;
    const size_t G_S    = (size_t)NN * 512;
    const size_t CM_S   = (size_t)CDIM * NN;

    // 1. xn1 = LN1(x)   (both batches)
    ln_kernel<<<dim3(NN / 256, 2), blk, 0, stream>>>(x, ln1_w, xn);
    // 2. qkv planes = qkv_wb @ xn1
    gemm_mfma<0, 0><<<dim3(NN / 64, 3, 2), dim3(192), shm192, stream>>>(
        qkv_wb, xn, nullptr, qkvb, 576, 192, 200, XN_S, QKV_S, 0, nullptr, nullptr);
    // 3. offsets = off_wb @ xn1
    gemm_mfma<1, 0><<<dim3(NN / 64, 1, 2), dim3(192), shm192, stream>>>(
        off_wb, xn, nullptr, offb, 72, 192, 200, XN_S, OFF_S, 0, nullptr, nullptr);
    // 4. deformable attention, PER BATCH (L2 working set 18.9 MB each)
    for (int b = 0; b < BB; ++b)
        attn_kernel<<<dim3(1024), blk, 0, stream>>>(
            qkvb + (size_t)b * QKV_S, offb + (size_t)b * OFF_S, rpb,
            attn + (size_t)b * APL_S);
    // 5. x1 = x + proj_wb @ attn -> d_out (f32) FUSED with LN2 -> xn2 (bf16)
    gemm_mfma<4, 1><<<dim3(NN / 64, 1, 2), dim3(192), shm192, stream>>>(
        proj_wb, attn, x, out, 192, 192, 200, APL_S, CM_S, CM_S, ln2_w, xn2);
    // 6. t = pi_wb @ xn2   ([N][1024], rows pre-remapped, O=1024)
    gemm_mfma<3, 0><<<dim3(NN / 64, 4, 2), blk, shm192, stream>>>(
        pi_wb, xn2, nullptr, t, 1024, 192, 200, XN_S, T_S, 0, nullptr, nullptr);
    // 7. g = gelu(dw(t1)) * dw(t2)   ([N][512], aliases qkvb)
    dwgate_kernel<<<dim3(NN * 64 / 256, 2), blk, 0, stream>>>(t, dwT, g);
    // 8. out = x1 + po_wb @ g   (in-place residual on d_out)
    gemm_mfma<2, 0><<<dim3(NN / 64, 1, 2), dim3(192), shm512, stream>>>(
        po_wb, g, out, out, 192, 512, 520, G_S, CM_S, CM_S, nullptr, nullptr);
}